// Round 8
// baseline (205.709 us; speedup 1.0000x reference)
//
#include <hip/hip_runtime.h>
#include <hip/hip_bf16.h>

typedef __bf16 bf16x8_t __attribute__((ext_vector_type(8)));
typedef float f32x4_t __attribute__((ext_vector_type(4)));
using bf16 = __hip_bfloat16;

__device__ __forceinline__ unsigned short f2bf_bits(float v) {
  __hip_bfloat16 h = __float2bfloat16(v);
  return *reinterpret_cast<unsigned short*>(&h);
}

// mish(x) = x*tanh(softplus(x)) = x*n/(n+2) with n = e^x*(e^x+2).
__device__ __forceinline__ float mish_f(float x) {
  float z = __expf(x);
  float n = z * (z + 2.0f);
  float m = x * n / (n + 2.0f);
  return (x > 10.0f) ? x : m;
}

// 13 cubic B-spline basis values (grid 10, k=3, [-2,2]) + mish -> 28B LDS
// region. R0 sparse-store version.
__device__ __forceinline__ void kan_feats28(bf16* dst, float x) {
  unsigned int* d32 = (unsigned int*)dst;
#pragma unroll
  for (int d = 0; d < 7; ++d) d32[d] = 0u;
  float t = (x + 3.2f) * 2.5f;
  if (t >= 0.0f && t < 16.0f) {
    float tf = floorf(t);
    int c = (int)tf;
    float u = t - tf;
    float um = 1.0f - u;
    float u2 = u * u, u3 = u2 * u;
    const float s6 = 1.0f / 6.0f;
    float w0 = um * um * um * s6;
    float w1 = (3.0f * u3 - 6.0f * u2 + 4.0f) * s6;
    float w2 = (-3.0f * u3 + 3.0f * u2 + 3.0f * u + 1.0f) * s6;
    float w3 = u3 * s6;
    int j0 = c - 3;
    if (j0 >= 0)               dst[j0]     = __float2bfloat16(w0);
    if (j0 >= -1 && j0 <= 11)  dst[j0 + 1] = __float2bfloat16(w1);
    if (j0 >= -2 && j0 <= 10)  dst[j0 + 2] = __float2bfloat16(w2);
    if (j0 <= 9)               dst[j0 + 3] = __float2bfloat16(w3);
  }
  dst[13] = __float2bfloat16(mish_f(x));
}

// Builds W1f, W2f, W3f — ALL MFMA-fragment-major. Frag s (global k-frag of 32)
// x ntg (group of 16 N-rows): 512 elements (1KB); element (n,quad,el) at
// (s*16+ntg)*512 + n*32 + quad*8 + el. Packed grid (322 blocks).
__global__ __launch_bounds__(256) void prep_all(
    const float* __restrict__ c1, const float* __restrict__ sb1, const float* __restrict__ sp1,
    const float* __restrict__ c2, const float* __restrict__ sb2, const float* __restrict__ sp2,
    const float* __restrict__ c3, const float* __restrict__ sb3, const float* __restrict__ sp3,
    bf16* __restrict__ W1f, bf16* __restrict__ W2f, bf16* __restrict__ W3f) {
  const int b = blockIdx.x, t = threadIdx.x;
  float vals[14];
  if (b < 49) {
    const int i = b, o = t;
    const int ntg = o >> 4, lrr = o & 15;
    const size_t io = (size_t)i * 256 + o;
    const float spv = sp1[io];
#pragma unroll
    for (int r = 0; r < 13; ++r) vals[r] = c1[io * 13 + r] * spv;
    vals[13] = sb1[io];
#pragma unroll
    for (int d = 0; d < 7; ++d) {
      const int k2 = i * 14 + 2 * d;
      const int s = k2 >> 5, r2 = k2 & 31;
      const size_t off = ((size_t)(s * 16 + ntg)) * 512 + lrr * 32 + (r2 >> 3) * 8 + (r2 & 7);
      *(unsigned int*)(W1f + off) = (unsigned int)f2bf_bits(vals[2 * d]) |
                                    ((unsigned int)f2bf_bits(vals[2 * d + 1]) << 16);
    }
  } else if (b == 49) {
    const int ntg = t >> 4, lrr = t & 15;
#pragma unroll
    for (int d = 0; d < 9; ++d) {
      const int k2 = 686 + 2 * d;
      const int r2 = k2 & 31;
      *(unsigned int*)(W1f + ((size_t)(21 * 16 + ntg)) * 512 + lrr * 32 + (r2 >> 3) * 8 + (r2 & 7)) = 0u;
    }
  } else if (b < 306) {
    const int i = b - 50;
    const int o = t;
    const int ntg = o >> 4, lrr = o & 15;
    const size_t io = (size_t)i * 256 + o;
    const float spv = sp2[io];
#pragma unroll
    for (int r = 0; r < 13; ++r) vals[r] = c2[io * 13 + r] * spv;
    vals[13] = sb2[io];
#pragma unroll
    for (int d = 0; d < 7; ++d) {
      const int k2 = i * 14 + 2 * d;
      const int s = k2 >> 5, r2 = k2 & 31;
      const size_t off = ((size_t)(s * 16 + ntg)) * 512 + lrr * 32 + (r2 >> 3) * 8 + (r2 & 7);
      *(unsigned int*)(W2f + off) = (unsigned int)f2bf_bits(vals[2 * d]) |
                                    ((unsigned int)f2bf_bits(vals[2 * d + 1]) << 16);
    }
  } else {
    const int idx = (b - 306) * 256 + t;  // 4096 items: i in [0,256), o in [0,16)
    const int i = idx >> 4, o = idx & 15;
    if (o < 10) {
      const size_t io = (size_t)i * 10 + o;
      const float spv = sp3[io];
#pragma unroll
      for (int r = 0; r < 13; ++r) vals[r] = c3[io * 13 + r] * spv;
      vals[13] = sb3[io];
#pragma unroll
      for (int d = 0; d < 7; ++d) {
        const int k2 = i * 14 + 2 * d;
        const int s = k2 >> 5, r2 = k2 & 31;
        const size_t off = (size_t)s * 512 + o * 32 + (r2 >> 3) * 8 + (r2 & 7);
        *(unsigned int*)(W3f + off) = (unsigned int)f2bf_bits(vals[2 * d]) |
                                      ((unsigned int)f2bf_bits(vals[2 * d + 1]) << 16);
      }
    } else {
#pragma unroll
      for (int d = 0; d < 7; ++d) {
        const int k2 = i * 14 + 2 * d;
        const int s = k2 >> 5, r2 = k2 & 31;
        *(unsigned int*)(W3f + (size_t)s * 512 + o * 32 + (r2 >> 3) * 8 + (r2 & 7)) = 0u;
      }
    }
  }
}

// Megakernel v13: TLP. 512 blocks x 16 images (M=16), 2 blocks/CU — the two
// blocks' phases interleave and hide each other's latency (7 rounds of
// intra-block scheduling all plateaued at ~50us with 1 block/CU, 38% occ).
// R0 k-step machinery verbatim (plain loads, 4-deep compiler-placed FIFO,
// __syncthreads); R7 super-chunk C/E (producers = 1 eval/thread/SC).
// LDS 52.5KB -> 2 blocks/CU; launch_bounds (1024,8) caps VGPR at 64.
__global__ __launch_bounds__(1024, 8) void meganet(
    const float* __restrict__ x, const bf16* __restrict__ W1f,
    const bf16* __restrict__ W2f, const bf16* __restrict__ W3f,
    const float* __restrict__ b1, const float* __restrict__ b2,
    const float* __restrict__ b3, float* __restrict__ out) {
  __shared__ __align__(16) char lds[53760];
  float* const Hs = (float*)lds;             // [256][20] f32 transposed (20480)
  bf16* const A0 = (bf16*)(lds + 20480);     // [16][472] bf16 (15104)
  bf16* const A1 = (bf16*)(lds + 35584);     // [16][472] bf16 (ends 50688)
  float* const P = (float*)(lds + 50176);    // [16][56] f32 (3584; dead before
                                             //  A1's C/E-extent use)
  float* const xs = (float*)lds;             // phase A only (50176)
  float* const Red = (float*)(lds + 20480);  // [7][16][16] f32 (E tail)
  float* const V = (float*)(lds + 35584);    // 16x16 f32

  const int t = threadIdx.x;
  const int w = t >> 6, lane = t & 63, quad = lane >> 4, lr = lane & 15;
  const int pr = t & 511;                    // producer linear id (t>=512)
  const int tr = pr >> 4, ej = pr & 15;      // B-phase eval coords (rows x 16)
  const int trc = pr >> 5, cj = pr & 31;     // C/E eval coords (rows x 32)
  const int r0 = blockIdx.x * 16;
  const int foff = lr * 32 + quad * 8;
  const bool cons = (w < 8);
  const int ntg0 = 2 * w;  // consumer col-group base (valid w<8)

  // ---- Phase A: pool 16 images -> P[16][56] (staged via LDS) ----
  {
    const float4* src = (const float4*)x + (size_t)r0 * 196;
    float4* xd = (float4*)xs;
#pragma unroll
    for (int l = 0; l < 4; ++l) {
      const int idx = t + l * 1024;
      if (idx < 3136) xd[idx] = src[idx];
    }
    __syncthreads();
    if (t < 784) {
      const int img = t / 49, p = t - img * 49;
      const int oh = p / 7, ow = p - oh * 7;
      const float* xi = xs + img * 784 + oh * 112 + ow * 4;
      f32x4_t s4 = (f32x4_t){0.f, 0.f, 0.f, 0.f};
#pragma unroll
      for (int rr = 0; rr < 4; ++rr) {
        const f32x4_t v = *(const f32x4_t*)(xi + rr * 28);  // 16B-aligned
        s4 += v;
      }
      P[img * 56 + p] = (s4[0] + s4[1] + s4[2] + s4[3]) * (1.0f / 16.0f);
    }
    __syncthreads();
  }

  f32x4_t acc[2];
  acc[0] = (f32x4_t){0.f, 0.f, 0.f, 0.f};
  acc[1] = acc[0];

  // ---- Phase B: layer-1, K=704 (22 k-frags: chunks 7,7,7,1; 16-col chunks,
  //      stride 232; buffers aliased onto A0/A1) ----
  bf16* const Bch0 = A0;
  bf16* const Bch1 = A1;
  bf16x8_t q0[4], q1[4];
  if (cons) {
#pragma unroll
    for (int s = 0; s < 4; ++s) {
      q0[s] = *(const bf16x8_t*)(W1f + (size_t)(s * 16 + ntg0) * 512 + foff);
      q1[s] = *(const bf16x8_t*)(W1f + (size_t)(s * 16 + ntg0 + 1) * 512 + foff);
    }
  } else if (pr < 256) {
    kan_feats28(Bch0 + tr * 232 + ej * 14, P[tr * 56 + ej]);  // chunk 0
  }
  __syncthreads();
#pragma unroll
  for (int c = 0; c < 4; ++c) {
    const bf16* const Ac = (c & 1) ? Bch1 : Bch0;
    bf16* const An = (c & 1) ? Bch0 : Bch1;
    if (cons) {
      const int nks = (c < 3) ? 7 : 1;
#pragma unroll
      for (int ks = 0; ks < 7; ++ks) {
        if (ks >= nks) continue;
        const int kk = c * 7 + ks;
        const int sl = kk & 3;
        bf16x8_t bb0 = q0[sl], bb1 = q1[sl];
        if (kk + 4 < 22) {
          q0[sl] = *(const bf16x8_t*)(W1f + (size_t)((kk + 4) * 16 + ntg0) * 512 + foff);
          q1[sl] = *(const bf16x8_t*)(W1f + (size_t)((kk + 4) * 16 + ntg0 + 1) * 512 + foff);
        }
        bf16x8_t a = *(const bf16x8_t*)(Ac + lr * 232 + ks * 32 + quad * 8);
        acc[0] = __builtin_amdgcn_mfma_f32_16x16x32_bf16(a, bb0, acc[0], 0, 0, 0);
        acc[1] = __builtin_amdgcn_mfma_f32_16x16x32_bf16(a, bb1, acc[1], 0, 0, 0);
      }
    } else if (pr < 256) {
      if (c < 2) {
        kan_feats28(An + tr * 232 + ej * 14, P[tr * 56 + (c + 1) * 16 + ej]);
      } else if (c == 2) {
        if (ej == 0) kan_feats28(An + tr * 232, P[tr * 56 + 48]);
        else if (ej == 1) {
          unsigned int* z = (unsigned int*)(An + tr * 232 + 14);
#pragma unroll
          for (int d = 0; d < 9; ++d) z[d] = 0u;  // pad k 686..703
        }
      }
    }
    __syncthreads();
  }
  // H1 = acc + b1 -> Hs (transposed [col][20]); consumers cover all 256 cols
  if (cons) {
#pragma unroll
    for (int n = 0; n < 2; ++n) {
      const int col = w * 32 + n * 16 + lr;
      const float bn = b1[col];
      f32x4_t v;
#pragma unroll
      for (int r = 0; r < 4; ++r) v[r] = acc[n][r] + bn;
      *(f32x4_t*)(Hs + col * 20 + quad * 4) = v;
    }
  }
  __syncthreads();

  // ---- Phase C: layer-2, K=3584. 8 super-chunks x 14 k-steps (32 H-cols,
  //      stride 472). Producers: 1 feats eval/thread per SC. ----
  acc[0] = (f32x4_t){0.f, 0.f, 0.f, 0.f};
  acc[1] = acc[0];
  if (cons) {
#pragma unroll
    for (int s = 0; s < 4; ++s) {
      q0[s] = *(const bf16x8_t*)(W2f + (size_t)(s * 16 + ntg0) * 512 + foff);
      q1[s] = *(const bf16x8_t*)(W2f + (size_t)(s * 16 + ntg0 + 1) * 512 + foff);
    }
  } else {  // SC0: cols 0..31
    kan_feats28(A0 + trc * 472 + cj * 14, Hs[cj * 20 + trc]);
  }
  __syncthreads();
#pragma unroll
  for (int S = 0; S < 8; ++S) {
    const bf16* const Ac = (S & 1) ? A1 : A0;
    bf16* const An = (S & 1) ? A0 : A1;
    if (cons) {
#pragma unroll
      for (int ks = 0; ks < 14; ++ks) {
        const int kk = S * 14 + ks;
        const int sl = kk & 3;
        bf16x8_t bb0 = q0[sl], bb1 = q1[sl];
        if (kk + 4 < 112) {
          q0[sl] = *(const bf16x8_t*)(W2f + (size_t)((kk + 4) * 16 + ntg0) * 512 + foff);
          q1[sl] = *(const bf16x8_t*)(W2f + (size_t)((kk + 4) * 16 + ntg0 + 1) * 512 + foff);
        }
        bf16x8_t a = *(const bf16x8_t*)(Ac + lr * 472 + ks * 32 + quad * 8);
        acc[0] = __builtin_amdgcn_mfma_f32_16x16x32_bf16(a, bb0, acc[0], 0, 0, 0);
        acc[1] = __builtin_amdgcn_mfma_f32_16x16x32_bf16(a, bb1, acc[1], 0, 0, 0);
      }
    } else if (S < 7) {
      const int col = 32 * (S + 1);
      kan_feats28(An + trc * 472 + cj * 14, Hs[(col + cj) * 20 + trc]);
    }
    __syncthreads();
  }
  // H2 = acc + b2 -> Hs (overwrite; H1 dead after SC7 feats)
  if (cons) {
#pragma unroll
    for (int n = 0; n < 2; ++n) {
      const int col = w * 32 + n * 16 + lr;
      const float bn = b2[col];
      f32x4_t v;
#pragma unroll
      for (int r = 0; r < 4; ++r) v[r] = acc[n][r] + bn;
      *(f32x4_t*)(Hs + col * 20 + quad * 4) = v;
    }
  }
  __syncthreads();

  // ---- Phase E: layer-3 (N=16, 10 real). 8 super-chunks; consumer waves
  //      0..6 do 2 k-steps each per SC (k-slots w and w+7); producers =
  //      waves 8..15 (1 eval/thread per SC). ----
  f32x4_t acc3 = (f32x4_t){0.f, 0.f, 0.f, 0.f};
  bf16x8_t q3[4];
  if (w < 7) {
#pragma unroll
    for (int s = 0; s < 4; ++s)
      q3[s] = *(const bf16x8_t*)(W3f + (size_t)(s * 7 + w) * 512 + foff);
  } else if (!cons) {  // SC0: cols 0..31
    kan_feats28(A0 + trc * 472 + cj * 14, Hs[cj * 20 + trc]);
  }
  __syncthreads();
#pragma unroll
  for (int S = 0; S < 8; ++S) {
    const bf16* const Ac = (S & 1) ? A1 : A0;
    bf16* const An = (S & 1) ? A0 : A1;
    if (w < 7) {
      {  // k-step 1: frag-chunk c0 = 2S, local ks = w
        const int c0 = 2 * S;
        bf16x8_t bb = q3[c0 & 3];
        if (c0 + 4 < 16)
          q3[c0 & 3] = *(const bf16x8_t*)(W3f + (size_t)((c0 + 4) * 7 + w) * 512 + foff);
        bf16x8_t a = *(const bf16x8_t*)(Ac + lr * 472 + w * 32 + quad * 8);
        acc3 = __builtin_amdgcn_mfma_f32_16x16x32_bf16(a, bb, acc3, 0, 0, 0);
      }
      {  // k-step 2: frag-chunk c1 = 2S+1, local ks = w+7
        const int c1 = 2 * S + 1;
        bf16x8_t bb = q3[c1 & 3];
        if (c1 + 4 < 16)
          q3[c1 & 3] = *(const bf16x8_t*)(W3f + (size_t)((c1 + 4) * 7 + w) * 512 + foff);
        bf16x8_t a = *(const bf16x8_t*)(Ac + lr * 472 + (w + 7) * 32 + quad * 8);
        acc3 = __builtin_amdgcn_mfma_f32_16x16x32_bf16(a, bb, acc3, 0, 0, 0);
      }
    } else if (!cons && S < 7) {
      const int col = 32 * (S + 1);
      kan_feats28(An + trc * 472 + cj * 14, Hs[(col + cj) * 20 + trc]);
    }
    __syncthreads();
  }
  if (w < 7) {
#pragma unroll
    for (int r = 0; r < 4; ++r)
      Red[w * 256 + (quad * 4 + r) * 16 + lr] = acc3[r];
  }
  __syncthreads();
  if (t < 256) {
    const int rr = t >> 4, oj = t & 15;
    float s = (oj < 10) ? b3[oj] : 0.f;
#pragma unroll
    for (int ks = 0; ks < 7; ++ks) s += Red[ks * 256 + rr * 16 + oj];
    V[rr * 16 + oj] = s;
  }
  __syncthreads();
  if (t < 16) {
    float vv[10];
#pragma unroll
    for (int o = 0; o < 10; ++o) vv[o] = V[t * 16 + o];
    float mx = vv[0];
#pragma unroll
    for (int o = 1; o < 10; ++o) mx = fmaxf(mx, vv[o]);
    float se = 0.f;
#pragma unroll
    for (int o = 0; o < 10; ++o) se += expf(vv[o] - mx);
    const float l = mx + logf(se);
#pragma unroll
    for (int o = 0; o < 10; ++o) out[(size_t)(r0 + t) * 10 + o] = vv[o] - l;
  }
}

extern "C" void kernel_launch(void* const* d_in, const int* in_sizes, int n_in,
                              void* d_out, int out_size, void* d_ws, size_t ws_size,
                              hipStream_t stream) {
  const float* x = (const float*)d_in[0];
  const float* coef1 = (const float*)d_in[1];
  const float* sb1 = (const float*)d_in[2];
  const float* sp1 = (const float*)d_in[3];
  const float* b1 = (const float*)d_in[4];
  const float* coef2 = (const float*)d_in[5];
  const float* sb2 = (const float*)d_in[6];
  const float* sp2 = (const float*)d_in[7];
  const float* b2 = (const float*)d_in[8];
  const float* coef3 = (const float*)d_in[9];
  const float* sb3 = (const float*)d_in[10];
  const float* sp3 = (const float*)d_in[11];
  const float* b3 = (const float*)d_in[12];
  float* out = (float*)d_out;

  char* ws = (char*)d_ws;
  bf16* W1f = (bf16*)ws;              // 22 frags x 16 ntg x 1KB = 360448 B
  bf16* W2f = (bf16*)(ws + 360448);   // 112 x 16 x 1KB = 1835008 B
  bf16* W3f = (bf16*)(ws + 2195456);  // 112 x 1KB = 114688 B

  prep_all<<<322, 256, 0, stream>>>(coef1, sb1, sp1, coef2, sb2, sp2,
                                    coef3, sb3, sp3, W1f, W2f, W3f);
  meganet<<<512, 1024, 0, stream>>>(x, W1f, W2f, W3f, b1, b2, b3, out);
}

// Round 9
// 170.800 us; speedup vs baseline: 1.2044x; 1.2044x over previous
//
#include <hip/hip_runtime.h>
#include <hip/hip_bf16.h>

typedef __bf16 bf16x8_t __attribute__((ext_vector_type(8)));
typedef float f32x4_t __attribute__((ext_vector_type(4)));
using bf16 = __hip_bfloat16;

__device__ __forceinline__ unsigned short f2bf_bits(float v) {
  __hip_bfloat16 h = __float2bfloat16(v);
  return *reinterpret_cast<unsigned short*>(&h);
}

// mish(x) = x*tanh(softplus(x)) = x*n/(n+2) with n = e^x*(e^x+2).
__device__ __forceinline__ float mish_f(float x) {
  float z = __expf(x);
  float n = z * (z + 2.0f);
  float m = x * n / (n + 2.0f);
  return (x > 10.0f) ? x : m;
}

// 13 cubic B-spline basis values (grid 10, k=3, [-2,2]) + mish -> 28B LDS
// region. R0 sparse-store version.
__device__ __forceinline__ void kan_feats28(bf16* dst, float x) {
  unsigned int* d32 = (unsigned int*)dst;
#pragma unroll
  for (int d = 0; d < 7; ++d) d32[d] = 0u;
  float t = (x + 3.2f) * 2.5f;
  if (t >= 0.0f && t < 16.0f) {
    float tf = floorf(t);
    int c = (int)tf;
    float u = t - tf;
    float um = 1.0f - u;
    float u2 = u * u, u3 = u2 * u;
    const float s6 = 1.0f / 6.0f;
    float w0 = um * um * um * s6;
    float w1 = (3.0f * u3 - 6.0f * u2 + 4.0f) * s6;
    float w2 = (-3.0f * u3 + 3.0f * u2 + 3.0f * u + 1.0f) * s6;
    float w3 = u3 * s6;
    int j0 = c - 3;
    if (j0 >= 0)               dst[j0]     = __float2bfloat16(w0);
    if (j0 >= -1 && j0 <= 11)  dst[j0 + 1] = __float2bfloat16(w1);
    if (j0 >= -2 && j0 <= 10)  dst[j0 + 2] = __float2bfloat16(w2);
    if (j0 <= 9)               dst[j0 + 3] = __float2bfloat16(w3);
  }
  dst[13] = __float2bfloat16(mish_f(x));
}

// Builds W1f, W2f, W3f — ALL MFMA-fragment-major. Frag s (global k-frag of 32)
// x ntg (group of 16 N-rows): 512 elements (1KB); element (n,quad,el) at
// (s*16+ntg)*512 + n*32 + quad*8 + el. Packed grid (322 blocks).
__global__ __launch_bounds__(256) void prep_all(
    const float* __restrict__ c1, const float* __restrict__ sb1, const float* __restrict__ sp1,
    const float* __restrict__ c2, const float* __restrict__ sb2, const float* __restrict__ sp2,
    const float* __restrict__ c3, const float* __restrict__ sb3, const float* __restrict__ sp3,
    bf16* __restrict__ W1f, bf16* __restrict__ W2f, bf16* __restrict__ W3f) {
  const int b = blockIdx.x, t = threadIdx.x;
  float vals[14];
  if (b < 49) {
    const int i = b, o = t;
    const int ntg = o >> 4, lrr = o & 15;
    const size_t io = (size_t)i * 256 + o;
    const float spv = sp1[io];
#pragma unroll
    for (int r = 0; r < 13; ++r) vals[r] = c1[io * 13 + r] * spv;
    vals[13] = sb1[io];
#pragma unroll
    for (int d = 0; d < 7; ++d) {
      const int k2 = i * 14 + 2 * d;
      const int s = k2 >> 5, r2 = k2 & 31;
      const size_t off = ((size_t)(s * 16 + ntg)) * 512 + lrr * 32 + (r2 >> 3) * 8 + (r2 & 7);
      *(unsigned int*)(W1f + off) = (unsigned int)f2bf_bits(vals[2 * d]) |
                                    ((unsigned int)f2bf_bits(vals[2 * d + 1]) << 16);
    }
  } else if (b == 49) {
    const int ntg = t >> 4, lrr = t & 15;
#pragma unroll
    for (int d = 0; d < 9; ++d) {
      const int k2 = 686 + 2 * d;
      const int r2 = k2 & 31;
      *(unsigned int*)(W1f + ((size_t)(21 * 16 + ntg)) * 512 + lrr * 32 + (r2 >> 3) * 8 + (r2 & 7)) = 0u;
    }
  } else if (b < 306) {
    const int i = b - 50;
    const int o = t;
    const int ntg = o >> 4, lrr = o & 15;
    const size_t io = (size_t)i * 256 + o;
    const float spv = sp2[io];
#pragma unroll
    for (int r = 0; r < 13; ++r) vals[r] = c2[io * 13 + r] * spv;
    vals[13] = sb2[io];
#pragma unroll
    for (int d = 0; d < 7; ++d) {
      const int k2 = i * 14 + 2 * d;
      const int s = k2 >> 5, r2 = k2 & 31;
      const size_t off = ((size_t)(s * 16 + ntg)) * 512 + lrr * 32 + (r2 >> 3) * 8 + (r2 & 7);
      *(unsigned int*)(W2f + off) = (unsigned int)f2bf_bits(vals[2 * d]) |
                                    ((unsigned int)f2bf_bits(vals[2 * d + 1]) << 16);
    }
  } else {
    const int idx = (b - 306) * 256 + t;  // 4096 items: i in [0,256), o in [0,16)
    const int i = idx >> 4, o = idx & 15;
    if (o < 10) {
      const size_t io = (size_t)i * 10 + o;
      const float spv = sp3[io];
#pragma unroll
      for (int r = 0; r < 13; ++r) vals[r] = c3[io * 13 + r] * spv;
      vals[13] = sb3[io];
#pragma unroll
      for (int d = 0; d < 7; ++d) {
        const int k2 = i * 14 + 2 * d;
        const int s = k2 >> 5, r2 = k2 & 31;
        const size_t off = (size_t)s * 512 + o * 32 + (r2 >> 3) * 8 + (r2 & 7);
        *(unsigned int*)(W3f + off) = (unsigned int)f2bf_bits(vals[2 * d]) |
                                      ((unsigned int)f2bf_bits(vals[2 * d + 1]) << 16);
      }
    } else {
#pragma unroll
      for (int d = 0; d < 7; ++d) {
        const int k2 = i * 14 + 2 * d;
        const int s = k2 >> 5, r2 = k2 & 31;
        *(unsigned int*)(W3f + (size_t)s * 512 + o * 32 + (r2 >> 3) * 8 + (r2 & 7)) = 0u;
      }
    }
  }
}

// Megakernel v14: TLP without forced caps. 512 blocks x 16 images (M=16);
// LDS 52.5KB and target VGPR <=64 so the HARDWARE co-schedules 2 blocks/CU
// (R8 proved occupancy rises to ~80%; its forced 64-cap spill is removed by
// using launch_bounds(1024,4) = R7's no-spill regime). FIFO depth 2 (q0[2])
// keeps natural VGPR under the 64 threshold; the 2nd resident block covers
// the shallower prefetch. R0 k-step machinery verbatim otherwise.
__global__ __launch_bounds__(1024, 4) void meganet(
    const float* __restrict__ x, const bf16* __restrict__ W1f,
    const bf16* __restrict__ W2f, const bf16* __restrict__ W3f,
    const float* __restrict__ b1, const float* __restrict__ b2,
    const float* __restrict__ b3, float* __restrict__ out) {
  __shared__ __align__(16) char lds[53760];
  float* const Hs = (float*)lds;             // [256][20] f32 transposed (20480)
  bf16* const A0 = (bf16*)(lds + 20480);     // [16][472] bf16 (15104)
  bf16* const A1 = (bf16*)(lds + 35584);     // [16][472] bf16 (ends 50688)
  float* const P = (float*)(lds + 50176);    // [16][56] f32 (3584)
  float* const xs = (float*)lds;             // phase A only (50176)
  float* const Red = (float*)(lds + 20480);  // [7][16][16] f32 (E tail)
  float* const V = (float*)(lds + 35584);    // 16x16 f32

  const int t = threadIdx.x;
  const int w = t >> 6, lane = t & 63, quad = lane >> 4, lr = lane & 15;
  const int pr = t & 511;                    // producer linear id (t>=512)
  const int tr = pr >> 4, ej = pr & 15;      // B-phase eval coords (rows x 16)
  const int trc = pr >> 5, cj = pr & 31;     // C/E eval coords (rows x 32)
  const int r0 = blockIdx.x * 16;
  const int foff = lr * 32 + quad * 8;
  const bool cons = (w < 8);
  const int ntg0 = 2 * w;  // consumer col-group base (valid w<8)

  // ---- Phase A: pool 16 images -> P[16][56] (staged via LDS) ----
  {
    const float4* src = (const float4*)x + (size_t)r0 * 196;
    float4* xd = (float4*)xs;
#pragma unroll
    for (int l = 0; l < 4; ++l) {
      const int idx = t + l * 1024;
      if (idx < 3136) xd[idx] = src[idx];
    }
    __syncthreads();
    if (t < 784) {
      const int img = t / 49, p = t - img * 49;
      const int oh = p / 7, ow = p - oh * 7;
      const float* xi = xs + img * 784 + oh * 112 + ow * 4;
      f32x4_t s4 = (f32x4_t){0.f, 0.f, 0.f, 0.f};
#pragma unroll
      for (int rr = 0; rr < 4; ++rr) {
        const f32x4_t v = *(const f32x4_t*)(xi + rr * 28);  // 16B-aligned
        s4 += v;
      }
      P[img * 56 + p] = (s4[0] + s4[1] + s4[2] + s4[3]) * (1.0f / 16.0f);
    }
    __syncthreads();
  }

  f32x4_t acc[2];
  acc[0] = (f32x4_t){0.f, 0.f, 0.f, 0.f};
  acc[1] = acc[0];

  // ---- Phase B: layer-1, K=704 (22 k-frags: chunks 7,7,7,1; 16-col chunks,
  //      stride 232; buffers aliased onto A0/A1) ----
  bf16* const Bch0 = A0;
  bf16* const Bch1 = A1;
  bf16x8_t q0[2], q1[2];
  if (cons) {
#pragma unroll
    for (int s = 0; s < 2; ++s) {
      q0[s] = *(const bf16x8_t*)(W1f + (size_t)(s * 16 + ntg0) * 512 + foff);
      q1[s] = *(const bf16x8_t*)(W1f + (size_t)(s * 16 + ntg0 + 1) * 512 + foff);
    }
  } else if (pr < 256) {
    kan_feats28(Bch0 + tr * 232 + ej * 14, P[tr * 56 + ej]);  // chunk 0
  }
  __syncthreads();
#pragma unroll
  for (int c = 0; c < 4; ++c) {
    const bf16* const Ac = (c & 1) ? Bch1 : Bch0;
    bf16* const An = (c & 1) ? Bch0 : Bch1;
    if (cons) {
      const int nks = (c < 3) ? 7 : 1;
#pragma unroll
      for (int ks = 0; ks < 7; ++ks) {
        if (ks >= nks) continue;
        const int kk = c * 7 + ks;
        const int sl = kk & 1;
        bf16x8_t bb0 = q0[sl], bb1 = q1[sl];
        if (kk + 2 < 22) {
          q0[sl] = *(const bf16x8_t*)(W1f + (size_t)((kk + 2) * 16 + ntg0) * 512 + foff);
          q1[sl] = *(const bf16x8_t*)(W1f + (size_t)((kk + 2) * 16 + ntg0 + 1) * 512 + foff);
        }
        bf16x8_t a = *(const bf16x8_t*)(Ac + lr * 232 + ks * 32 + quad * 8);
        acc[0] = __builtin_amdgcn_mfma_f32_16x16x32_bf16(a, bb0, acc[0], 0, 0, 0);
        acc[1] = __builtin_amdgcn_mfma_f32_16x16x32_bf16(a, bb1, acc[1], 0, 0, 0);
      }
    } else if (pr < 256) {
      if (c < 2) {
        kan_feats28(An + tr * 232 + ej * 14, P[tr * 56 + (c + 1) * 16 + ej]);
      } else if (c == 2) {
        if (ej == 0) kan_feats28(An + tr * 232, P[tr * 56 + 48]);
        else if (ej == 1) {
          unsigned int* z = (unsigned int*)(An + tr * 232 + 14);
#pragma unroll
          for (int d = 0; d < 9; ++d) z[d] = 0u;  // pad k 686..703
        }
      }
    }
    __syncthreads();
  }
  // H1 = acc + b1 -> Hs (transposed [col][20]); consumers cover all 256 cols
  if (cons) {
#pragma unroll
    for (int n = 0; n < 2; ++n) {
      const int col = w * 32 + n * 16 + lr;
      const float bn = b1[col];
      f32x4_t v;
#pragma unroll
      for (int r = 0; r < 4; ++r) v[r] = acc[n][r] + bn;
      *(f32x4_t*)(Hs + col * 20 + quad * 4) = v;
    }
  }
  __syncthreads();

  // ---- Phase C: layer-2, K=3584. 8 super-chunks x 14 k-steps (32 H-cols,
  //      stride 472). Producers: 1 feats eval/thread per SC. ----
  acc[0] = (f32x4_t){0.f, 0.f, 0.f, 0.f};
  acc[1] = acc[0];
  if (cons) {
#pragma unroll
    for (int s = 0; s < 2; ++s) {
      q0[s] = *(const bf16x8_t*)(W2f + (size_t)(s * 16 + ntg0) * 512 + foff);
      q1[s] = *(const bf16x8_t*)(W2f + (size_t)(s * 16 + ntg0 + 1) * 512 + foff);
    }
  } else {  // SC0: cols 0..31
    kan_feats28(A0 + trc * 472 + cj * 14, Hs[cj * 20 + trc]);
  }
  __syncthreads();
#pragma unroll
  for (int S = 0; S < 8; ++S) {
    const bf16* const Ac = (S & 1) ? A1 : A0;
    bf16* const An = (S & 1) ? A0 : A1;
    if (cons) {
#pragma unroll
      for (int ks = 0; ks < 14; ++ks) {
        const int kk = S * 14 + ks;
        const int sl = kk & 1;
        bf16x8_t bb0 = q0[sl], bb1 = q1[sl];
        if (kk + 2 < 112) {
          q0[sl] = *(const bf16x8_t*)(W2f + (size_t)((kk + 2) * 16 + ntg0) * 512 + foff);
          q1[sl] = *(const bf16x8_t*)(W2f + (size_t)((kk + 2) * 16 + ntg0 + 1) * 512 + foff);
        }
        bf16x8_t a = *(const bf16x8_t*)(Ac + lr * 472 + ks * 32 + quad * 8);
        acc[0] = __builtin_amdgcn_mfma_f32_16x16x32_bf16(a, bb0, acc[0], 0, 0, 0);
        acc[1] = __builtin_amdgcn_mfma_f32_16x16x32_bf16(a, bb1, acc[1], 0, 0, 0);
      }
    } else if (S < 7) {
      const int col = 32 * (S + 1);
      kan_feats28(An + trc * 472 + cj * 14, Hs[(col + cj) * 20 + trc]);
    }
    __syncthreads();
  }
  // H2 = acc + b2 -> Hs (overwrite; H1 dead after SC7 feats)
  if (cons) {
#pragma unroll
    for (int n = 0; n < 2; ++n) {
      const int col = w * 32 + n * 16 + lr;
      const float bn = b2[col];
      f32x4_t v;
#pragma unroll
      for (int r = 0; r < 4; ++r) v[r] = acc[n][r] + bn;
      *(f32x4_t*)(Hs + col * 20 + quad * 4) = v;
    }
  }
  __syncthreads();

  // ---- Phase E: layer-3 (N=16, 10 real). 8 super-chunks; consumer waves
  //      0..6 do 2 k-steps each per SC (chunks 2S, 2S+1 at k-slot w);
  //      producers = waves 8..15 (1 eval/thread per SC). ----
  f32x4_t acc3 = (f32x4_t){0.f, 0.f, 0.f, 0.f};
  bf16x8_t q3[2];
  if (w < 7) {
#pragma unroll
    for (int s = 0; s < 2; ++s)
      q3[s] = *(const bf16x8_t*)(W3f + (size_t)(s * 7 + w) * 512 + foff);
  } else if (!cons) {  // SC0: cols 0..31
    kan_feats28(A0 + trc * 472 + cj * 14, Hs[cj * 20 + trc]);
  }
  __syncthreads();
#pragma unroll
  for (int S = 0; S < 8; ++S) {
    const bf16* const Ac = (S & 1) ? A1 : A0;
    bf16* const An = (S & 1) ? A0 : A1;
    if (w < 7) {
      {  // k-step 1: frag-chunk c0 = 2S, local ks = w
        const int c0 = 2 * S;
        bf16x8_t bb = q3[c0 & 1];
        if (c0 + 2 < 16)
          q3[c0 & 1] = *(const bf16x8_t*)(W3f + (size_t)((c0 + 2) * 7 + w) * 512 + foff);
        bf16x8_t a = *(const bf16x8_t*)(Ac + lr * 472 + w * 32 + quad * 8);
        acc3 = __builtin_amdgcn_mfma_f32_16x16x32_bf16(a, bb, acc3, 0, 0, 0);
      }
      {  // k-step 2: frag-chunk c1 = 2S+1, local ks = w+7
        const int c1 = 2 * S + 1;
        bf16x8_t bb = q3[c1 & 1];
        if (c1 + 2 < 16)
          q3[c1 & 1] = *(const bf16x8_t*)(W3f + (size_t)((c1 + 2) * 7 + w) * 512 + foff);
        bf16x8_t a = *(const bf16x8_t*)(Ac + lr * 472 + (w + 7) * 32 + quad * 8);
        acc3 = __builtin_amdgcn_mfma_f32_16x16x32_bf16(a, bb, acc3, 0, 0, 0);
      }
    } else if (!cons && S < 7) {
      const int col = 32 * (S + 1);
      kan_feats28(An + trc * 472 + cj * 14, Hs[(col + cj) * 20 + trc]);
    }
    __syncthreads();
  }
  if (w < 7) {
#pragma unroll
    for (int r = 0; r < 4; ++r)
      Red[w * 256 + (quad * 4 + r) * 16 + lr] = acc3[r];
  }
  __syncthreads();
  if (t < 256) {
    const int rr = t >> 4, oj = t & 15;
    float s = (oj < 10) ? b3[oj] : 0.f;
#pragma unroll
    for (int ks = 0; ks < 7; ++ks) s += Red[ks * 256 + rr * 16 + oj];
    V[rr * 16 + oj] = s;
  }
  __syncthreads();
  if (t < 16) {
    float vv[10];
#pragma unroll
    for (int o = 0; o < 10; ++o) vv[o] = V[t * 16 + o];
    float mx = vv[0];
#pragma unroll
    for (int o = 1; o < 10; ++o) mx = fmaxf(mx, vv[o]);
    float se = 0.f;
#pragma unroll
    for (int o = 0; o < 10; ++o) se += expf(vv[o] - mx);
    const float l = mx + logf(se);
#pragma unroll
    for (int o = 0; o < 10; ++o) out[(size_t)(r0 + t) * 10 + o] = vv[o] - l;
  }
}

extern "C" void kernel_launch(void* const* d_in, const int* in_sizes, int n_in,
                              void* d_out, int out_size, void* d_ws, size_t ws_size,
                              hipStream_t stream) {
  const float* x = (const float*)d_in[0];
  const float* coef1 = (const float*)d_in[1];
  const float* sb1 = (const float*)d_in[2];
  const float* sp1 = (const float*)d_in[3];
  const float* b1 = (const float*)d_in[4];
  const float* coef2 = (const float*)d_in[5];
  const float* sb2 = (const float*)d_in[6];
  const float* sp2 = (const float*)d_in[7];
  const float* b2 = (const float*)d_in[8];
  const float* coef3 = (const float*)d_in[9];
  const float* sb3 = (const float*)d_in[10];
  const float* sp3 = (const float*)d_in[11];
  const float* b3 = (const float*)d_in[12];
  float* out = (float*)d_out;

  char* ws = (char*)d_ws;
  bf16* W1f = (bf16*)ws;              // 22 frags x 16 ntg x 1KB = 360448 B
  bf16* W2f = (bf16*)(ws + 360448);   // 112 x 16 x 1KB = 1835008 B
  bf16* W3f = (bf16*)(ws + 2195456);  // 112 x 1KB = 114688 B

  prep_all<<<322, 256, 0, stream>>>(coef1, sb1, sp1, coef2, sb2, sp2,
                                    coef3, sb3, sp3, W1f, W2f, W3f);
  meganet<<<512, 1024, 0, stream>>>(x, W1f, W2f, W3f, b1, b2, b3, out);
}

// Round 10
// 160.761 us; speedup vs baseline: 1.2796x; 1.0624x over previous
//
#include <hip/hip_runtime.h>
#include <hip/hip_bf16.h>

typedef __bf16 bf16x8_t __attribute__((ext_vector_type(8)));
typedef float f32x4_t __attribute__((ext_vector_type(4)));
using bf16 = __hip_bfloat16;

__device__ __forceinline__ unsigned short f2bf_bits(float v) {
  __hip_bfloat16 h = __float2bfloat16(v);
  return *reinterpret_cast<unsigned short*>(&h);
}

// mish(x) = x*tanh(softplus(x)) = x*n/(n+2) with n = e^x*(e^x+2).
__device__ __forceinline__ float mish_f(float x) {
  float z = __expf(x);
  float n = z * (z + 2.0f);
  float m = x * n / (n + 2.0f);
  return (x > 10.0f) ? x : m;
}

// 13 cubic B-spline basis values (grid 10, k=3, [-2,2]) + mish -> 28B LDS
// region. R0 sparse-store version.
__device__ __forceinline__ void kan_feats28(bf16* dst, float x) {
  unsigned int* d32 = (unsigned int*)dst;
#pragma unroll
  for (int d = 0; d < 7; ++d) d32[d] = 0u;
  float t = (x + 3.2f) * 2.5f;
  if (t >= 0.0f && t < 16.0f) {
    float tf = floorf(t);
    int c = (int)tf;
    float u = t - tf;
    float um = 1.0f - u;
    float u2 = u * u, u3 = u2 * u;
    const float s6 = 1.0f / 6.0f;
    float w0 = um * um * um * s6;
    float w1 = (3.0f * u3 - 6.0f * u2 + 4.0f) * s6;
    float w2 = (-3.0f * u3 + 3.0f * u2 + 3.0f * u + 1.0f) * s6;
    float w3 = u3 * s6;
    int j0 = c - 3;
    if (j0 >= 0)               dst[j0]     = __float2bfloat16(w0);
    if (j0 >= -1 && j0 <= 11)  dst[j0 + 1] = __float2bfloat16(w1);
    if (j0 >= -2 && j0 <= 10)  dst[j0 + 2] = __float2bfloat16(w2);
    if (j0 <= 9)               dst[j0 + 3] = __float2bfloat16(w3);
  }
  dst[13] = __float2bfloat16(mish_f(x));
}

// One consumer k-step: use slot SLOT (literal token -> named registers, no
// arrays, rule-#20-proof), reload the same slot for k-frag KK+7 (used 7
// steps later => depth-7 latency pipeline; T_step ~ L/7).
#define KS2(WPTR, LDA, NKTOT, AC, KK, KS, SLOT)                                \
  do {                                                                         \
    bf16x8_t bb0_ = q0_##SLOT, bb1_ = q1_##SLOT;                               \
    if ((KK) + 7 < (NKTOT)) {                                                  \
      const bf16* p_ = (WPTR) + (size_t)(((KK) + 7) * 16 + ntg0) * 512 + foff; \
      q0_##SLOT = *(const bf16x8_t*)p_;                                        \
      q1_##SLOT = *(const bf16x8_t*)(p_ + 512);                                \
    }                                                                          \
    bf16x8_t a0_ = *(const bf16x8_t*)((AC) + lr * (LDA) + (KS) * 32 + quad * 8); \
    bf16x8_t a1_ =                                                             \
        *(const bf16x8_t*)((AC) + (16 + lr) * (LDA) + (KS) * 32 + quad * 8);   \
    acc[0][0] = __builtin_amdgcn_mfma_f32_16x16x32_bf16(a0_, bb0_, acc[0][0], 0, 0, 0); \
    acc[0][1] = __builtin_amdgcn_mfma_f32_16x16x32_bf16(a0_, bb1_, acc[0][1], 0, 0, 0); \
    acc[1][0] = __builtin_amdgcn_mfma_f32_16x16x32_bf16(a1_, bb0_, acc[1][0], 0, 0, 0); \
    acc[1][1] = __builtin_amdgcn_mfma_f32_16x16x32_bf16(a1_, bb1_, acc[1][1], 0, 0, 0); \
  } while (0)

// 7-slot prologue fill: slot s <- k-frag s of WPTR.
#define QFILL7(WPTR)                                                           \
  do {                                                                         \
    const bf16* pB_ = (WPTR) + (size_t)ntg0 * 512 + foff;                      \
    q0_0 = *(const bf16x8_t*)(pB_);            q1_0 = *(const bf16x8_t*)(pB_ + 512); \
    q0_1 = *(const bf16x8_t*)(pB_ + 16 * 512); q1_1 = *(const bf16x8_t*)(pB_ + 17 * 512); \
    q0_2 = *(const bf16x8_t*)(pB_ + 32 * 512); q1_2 = *(const bf16x8_t*)(pB_ + 33 * 512); \
    q0_3 = *(const bf16x8_t*)(pB_ + 48 * 512); q1_3 = *(const bf16x8_t*)(pB_ + 49 * 512); \
    q0_4 = *(const bf16x8_t*)(pB_ + 64 * 512); q1_4 = *(const bf16x8_t*)(pB_ + 65 * 512); \
    q0_5 = *(const bf16x8_t*)(pB_ + 80 * 512); q1_5 = *(const bf16x8_t*)(pB_ + 81 * 512); \
    q0_6 = *(const bf16x8_t*)(pB_ + 96 * 512); q1_6 = *(const bf16x8_t*)(pB_ + 97 * 512); \
  } while (0)

// 7 k-steps of a phase-B chunk (kk = (C)*7 + ks, slot = ks).
#define B_CHUNK7(AC, C)                                                        \
  do {                                                                         \
    KS2(W1f, 232, 22, AC, (C) * 7 + 0, 0, 0);                                  \
    KS2(W1f, 232, 22, AC, (C) * 7 + 1, 1, 1);                                  \
    KS2(W1f, 232, 22, AC, (C) * 7 + 2, 2, 2);                                  \
    KS2(W1f, 232, 22, AC, (C) * 7 + 3, 3, 3);                                  \
    KS2(W1f, 232, 22, AC, (C) * 7 + 4, 4, 4);                                  \
    KS2(W1f, 232, 22, AC, (C) * 7 + 5, 5, 5);                                  \
    KS2(W1f, 232, 22, AC, (C) * 7 + 6, 6, 6);                                  \
  } while (0)

// 14 k-steps of a phase-C super-chunk (kk = (S)*14 + ks, slot = ks % 7).
#define C_SC14(AC, S)                                                          \
  do {                                                                         \
    KS2(W2f, 472, 112, AC, (S) * 14 + 0,  0,  0);                              \
    KS2(W2f, 472, 112, AC, (S) * 14 + 1,  1,  1);                              \
    KS2(W2f, 472, 112, AC, (S) * 14 + 2,  2,  2);                              \
    KS2(W2f, 472, 112, AC, (S) * 14 + 3,  3,  3);                              \
    KS2(W2f, 472, 112, AC, (S) * 14 + 4,  4,  4);                              \
    KS2(W2f, 472, 112, AC, (S) * 14 + 5,  5,  5);                              \
    KS2(W2f, 472, 112, AC, (S) * 14 + 6,  6,  6);                              \
    KS2(W2f, 472, 112, AC, (S) * 14 + 7,  7,  0);                              \
    KS2(W2f, 472, 112, AC, (S) * 14 + 8,  8,  1);                              \
    KS2(W2f, 472, 112, AC, (S) * 14 + 9,  9,  2);                              \
    KS2(W2f, 472, 112, AC, (S) * 14 + 10, 10, 3);                              \
    KS2(W2f, 472, 112, AC, (S) * 14 + 11, 11, 4);                              \
    KS2(W2f, 472, 112, AC, (S) * 14 + 12, 12, 5);                              \
    KS2(W2f, 472, 112, AC, (S) * 14 + 13, 13, 6);                              \
  } while (0)

// Builds W1f, W2f, W3f — ALL MFMA-fragment-major. Frag s (global k-frag of 32)
// x ntg (group of 16 N-rows): 512 elements (1KB); element (n,quad,el) at
// (s*16+ntg)*512 + n*32 + quad*8 + el. Packed grid (322 blocks).
__global__ __launch_bounds__(256) void prep_all(
    const float* __restrict__ c1, const float* __restrict__ sb1, const float* __restrict__ sp1,
    const float* __restrict__ c2, const float* __restrict__ sb2, const float* __restrict__ sp2,
    const float* __restrict__ c3, const float* __restrict__ sb3, const float* __restrict__ sp3,
    bf16* __restrict__ W1f, bf16* __restrict__ W2f, bf16* __restrict__ W3f) {
  const int b = blockIdx.x, t = threadIdx.x;
  float vals[14];
  if (b < 49) {
    const int i = b, o = t;
    const int ntg = o >> 4, lrr = o & 15;
    const size_t io = (size_t)i * 256 + o;
    const float spv = sp1[io];
#pragma unroll
    for (int r = 0; r < 13; ++r) vals[r] = c1[io * 13 + r] * spv;
    vals[13] = sb1[io];
#pragma unroll
    for (int d = 0; d < 7; ++d) {
      const int k2 = i * 14 + 2 * d;
      const int s = k2 >> 5, r2 = k2 & 31;
      const size_t off = ((size_t)(s * 16 + ntg)) * 512 + lrr * 32 + (r2 >> 3) * 8 + (r2 & 7);
      *(unsigned int*)(W1f + off) = (unsigned int)f2bf_bits(vals[2 * d]) |
                                    ((unsigned int)f2bf_bits(vals[2 * d + 1]) << 16);
    }
  } else if (b == 49) {
    const int ntg = t >> 4, lrr = t & 15;
#pragma unroll
    for (int d = 0; d < 9; ++d) {
      const int k2 = 686 + 2 * d;
      const int r2 = k2 & 31;
      *(unsigned int*)(W1f + ((size_t)(21 * 16 + ntg)) * 512 + lrr * 32 + (r2 >> 3) * 8 + (r2 & 7)) = 0u;
    }
  } else if (b < 306) {
    const int i = b - 50;
    const int o = t;
    const int ntg = o >> 4, lrr = o & 15;
    const size_t io = (size_t)i * 256 + o;
    const float spv = sp2[io];
#pragma unroll
    for (int r = 0; r < 13; ++r) vals[r] = c2[io * 13 + r] * spv;
    vals[13] = sb2[io];
#pragma unroll
    for (int d = 0; d < 7; ++d) {
      const int k2 = i * 14 + 2 * d;
      const int s = k2 >> 5, r2 = k2 & 31;
      const size_t off = ((size_t)(s * 16 + ntg)) * 512 + lrr * 32 + (r2 >> 3) * 8 + (r2 & 7);
      *(unsigned int*)(W2f + off) = (unsigned int)f2bf_bits(vals[2 * d]) |
                                    ((unsigned int)f2bf_bits(vals[2 * d + 1]) << 16);
    }
  } else {
    const int idx = (b - 306) * 256 + t;  // 4096 items: i in [0,256), o in [0,16)
    const int i = idx >> 4, o = idx & 15;
    if (o < 10) {
      const size_t io = (size_t)i * 10 + o;
      const float spv = sp3[io];
#pragma unroll
      for (int r = 0; r < 13; ++r) vals[r] = c3[io * 13 + r] * spv;
      vals[13] = sb3[io];
#pragma unroll
      for (int d = 0; d < 7; ++d) {
        const int k2 = i * 14 + 2 * d;
        const int s = k2 >> 5, r2 = k2 & 31;
        const size_t off = (size_t)s * 512 + o * 32 + (r2 >> 3) * 8 + (r2 & 7);
        *(unsigned int*)(W3f + off) = (unsigned int)f2bf_bits(vals[2 * d]) |
                                      ((unsigned int)f2bf_bits(vals[2 * d + 1]) << 16);
      }
    } else {
#pragma unroll
      for (int d = 0; d < 7; ++d) {
        const int k2 = i * 14 + 2 * d;
        const int s = k2 >> 5, r2 = k2 & 31;
        *(unsigned int*)(W3f + (size_t)s * 512 + o * 32 + (r2 >> 3) * 8 + (r2 & 7)) = 0u;
      }
    }
  }
}

// Megakernel v15: R7 geometry (M=32, 256 blocks, super-chunk C/E, plain
// loads, __syncthreads) + DEPTH-7 weight FIFO in NAMED registers (no arrays,
// literal slot tokens -> no rule-#20 scratch risk). R9's depth-2 regression
// vs R7's depth-4 fit T_step ~ L/depth with L~2000cy; depth 7 -> ~290cy.
__global__ __launch_bounds__(1024, 4) void meganet(
    const float* __restrict__ x, const bf16* __restrict__ W1f,
    const bf16* __restrict__ W2f, const bf16* __restrict__ W3f,
    const float* __restrict__ b1, const float* __restrict__ b2,
    const float* __restrict__ b3, float* __restrict__ out) {
  __shared__ __align__(16) char lds[104448];
  float* const Hs = (float*)lds;             // [256][36] f32 transposed (36864)
  bf16* const A0 = (bf16*)(lds + 36864);     // [32][472] bf16 (30208)
  bf16* const A1 = (bf16*)(lds + 67072);     // [32][472] bf16 (30208)
  float* const P = (float*)(lds + 97280);    // [32][56] f32 (7168)
  float* const xs = (float*)lds;             // phase A only (50176)
  float* const Red = (float*)(lds + 36864);  // [7][32][16] f32 (E tail)
  float* const V = (float*)(lds + 67072);    // 32x16 f32

  const int t = threadIdx.x;
  const int w = t >> 6, lane = t & 63, quad = lane >> 4, lr = lane & 15;
  const int tr = (t >> 4) & 31, ej = t & 15;  // producer eval coords (t>=512)
  const int r0 = blockIdx.x * 32;
  const int foff = lr * 32 + quad * 8;
  const bool cons = (w < 8);
  const int ntg0 = 2 * w;  // consumer col-group base (valid w<8)

  // ---- Phase A: pool 32 images -> P[32][56] (staged via LDS) ----
  for (int h = 0; h < 2; ++h) {
    const float4* src = (const float4*)x + (size_t)(r0 + h * 16) * 196;
    float4* xd = (float4*)xs;
#pragma unroll
    for (int l = 0; l < 4; ++l) {
      const int idx = t + l * 1024;
      if (idx < 3136) xd[idx] = src[idx];
    }
    __syncthreads();
    if (t < 784) {
      const int img = t / 49, p = t - img * 49;
      const int oh = p / 7, ow = p - oh * 7;
      const float* xi = xs + img * 784 + oh * 112 + ow * 4;
      f32x4_t s4 = (f32x4_t){0.f, 0.f, 0.f, 0.f};
#pragma unroll
      for (int rr = 0; rr < 4; ++rr) {
        const f32x4_t v = *(const f32x4_t*)(xi + rr * 28);  // 16B-aligned
        s4 += v;
      }
      P[(h * 16 + img) * 56 + p] = (s4[0] + s4[1] + s4[2] + s4[3]) * (1.0f / 16.0f);
    }
    __syncthreads();
  }

  f32x4_t acc[2][2];
#pragma unroll
  for (int m = 0; m < 2; ++m)
#pragma unroll
    for (int n = 0; n < 2; ++n) acc[m][n] = (f32x4_t){0.f, 0.f, 0.f, 0.f};

  // Depth-7 FIFO: named registers only.
  bf16x8_t q0_0, q0_1, q0_2, q0_3, q0_4, q0_5, q0_6;
  bf16x8_t q1_0, q1_1, q1_2, q1_3, q1_4, q1_5, q1_6;

  // ---- Phase B: layer-1, K=704 (22 k-frags; chunks 7,7,7,1; stride 232) ----
  bf16* const Bch0 = A0;
  bf16* const Bch1 = A1;
  if (cons) {
    QFILL7(W1f);
  } else {
    kan_feats28(Bch0 + tr * 232 + ej * 14, P[tr * 56 + ej]);  // chunk 0
  }
  __syncthreads();
#pragma unroll
  for (int c = 0; c < 4; ++c) {
    const bf16* const Ac = (c & 1) ? Bch1 : Bch0;
    bf16* const An = (c & 1) ? Bch0 : Bch1;
    if (cons) {
      if (c < 3) {
        B_CHUNK7(Ac, c);
      } else {
        KS2(W1f, 232, 22, Ac, 21, 0, 0);
      }
    } else {
      if (c < 2) {
        kan_feats28(An + tr * 232 + ej * 14, P[tr * 56 + (c + 1) * 16 + ej]);
      } else if (c == 2) {
        if (ej == 0) kan_feats28(An + tr * 232, P[tr * 56 + 48]);
        else if (ej == 1) {
          unsigned int* z = (unsigned int*)(An + tr * 232 + 14);
#pragma unroll
          for (int d = 0; d < 9; ++d) z[d] = 0u;  // pad k 686..703
        }
      }
    }
    __syncthreads();
  }
  // H1 = acc + b1 -> Hs (transposed); consumers cover all 256 cols
  if (cons) {
#pragma unroll
    for (int m = 0; m < 2; ++m)
#pragma unroll
      for (int n = 0; n < 2; ++n) {
        const int col = w * 32 + n * 16 + lr;
        const float bn = b1[col];
        f32x4_t v;
#pragma unroll
        for (int r = 0; r < 4; ++r) v[r] = acc[m][n][r] + bn;
        *(f32x4_t*)(Hs + col * 36 + m * 16 + quad * 4) = v;
      }
  }
  __syncthreads();

  // ---- Phase C: layer-2, K=3584. 8 super-chunks x 14 k-steps (32 H-cols,
  //      stride 472). Producers: 2 feats evals/thread per SC. ----
#pragma unroll
  for (int m = 0; m < 2; ++m)
#pragma unroll
    for (int n = 0; n < 2; ++n) acc[m][n] = (f32x4_t){0.f, 0.f, 0.f, 0.f};
  if (cons) {
    QFILL7(W2f);
  } else {  // SC0: cols 0..31
    kan_feats28(A0 + tr * 472 + ej * 14, Hs[ej * 36 + tr]);
    kan_feats28(A0 + tr * 472 + (16 + ej) * 14, Hs[(16 + ej) * 36 + tr]);
  }
  __syncthreads();
#pragma unroll
  for (int S = 0; S < 8; ++S) {
    const bf16* const Ac = (S & 1) ? A1 : A0;
    bf16* const An = (S & 1) ? A0 : A1;
    if (cons) {
      C_SC14(Ac, S);
    } else if (S < 7) {
      const int col = 32 * (S + 1);
      kan_feats28(An + tr * 472 + ej * 14, Hs[(col + ej) * 36 + tr]);
      kan_feats28(An + tr * 472 + (16 + ej) * 14, Hs[(col + 16 + ej) * 36 + tr]);
    }
    __syncthreads();
  }
  // H2 = acc + b2 -> Hs (overwrite; H1 dead after SC7 feats)
  if (cons) {
#pragma unroll
    for (int m = 0; m < 2; ++m)
#pragma unroll
      for (int n = 0; n < 2; ++n) {
        const int col = w * 32 + n * 16 + lr;
        const float bn = b2[col];
        f32x4_t v;
#pragma unroll
        for (int r = 0; r < 4; ++r) v[r] = acc[m][n][r] + bn;
        *(f32x4_t*)(Hs + col * 36 + m * 16 + quad * 4) = v;
      }
  }
  __syncthreads();

  // ---- Phase E: layer-3 (N=16, 10 real). 8 super-chunks; consumer waves
  //      0..6 do 2 k-steps each per SC (k-slots w and w+7); producers =
  //      waves 8..15 (2 feats evals/thread per SC). R7 verbatim. ----
  f32x4_t acc3[2];
  acc3[0] = (f32x4_t){0.f, 0.f, 0.f, 0.f};
  acc3[1] = acc3[0];
  bf16x8_t q3[4];
  if (w < 7) {
#pragma unroll
    for (int s = 0; s < 4; ++s)
      q3[s] = *(const bf16x8_t*)(W3f + (size_t)(s * 7 + w) * 512 + foff);
  } else if (!cons) {  // SC0: cols 0..31
    kan_feats28(A0 + tr * 472 + ej * 14, Hs[ej * 36 + tr]);
    kan_feats28(A0 + tr * 472 + (16 + ej) * 14, Hs[(16 + ej) * 36 + tr]);
  }
  __syncthreads();
#pragma unroll
  for (int S = 0; S < 8; ++S) {
    const bf16* const Ac = (S & 1) ? A1 : A0;
    bf16* const An = (S & 1) ? A0 : A1;
    if (w < 7) {
      {  // k-step 1: frag-chunk c0 = 2S, local ks = w
        const int c0 = 2 * S;
        bf16x8_t bb = q3[c0 & 3];
        if (c0 + 4 < 16)
          q3[c0 & 3] = *(const bf16x8_t*)(W3f + (size_t)((c0 + 4) * 7 + w) * 512 + foff);
        bf16x8_t a0 = *(const bf16x8_t*)(Ac + lr * 472 + w * 32 + quad * 8);
        bf16x8_t a1 = *(const bf16x8_t*)(Ac + (16 + lr) * 472 + w * 32 + quad * 8);
        acc3[0] = __builtin_amdgcn_mfma_f32_16x16x32_bf16(a0, bb, acc3[0], 0, 0, 0);
        acc3[1] = __builtin_amdgcn_mfma_f32_16x16x32_bf16(a1, bb, acc3[1], 0, 0, 0);
      }
      {  // k-step 2: frag-chunk c1 = 2S+1, local ks = w+7
        const int c1 = 2 * S + 1;
        bf16x8_t bb = q3[c1 & 3];
        if (c1 + 4 < 16)
          q3[c1 & 3] = *(const bf16x8_t*)(W3f + (size_t)((c1 + 4) * 7 + w) * 512 + foff);
        bf16x8_t a0 = *(const bf16x8_t*)(Ac + lr * 472 + (w + 7) * 32 + quad * 8);
        bf16x8_t a1 = *(const bf16x8_t*)(Ac + (16 + lr) * 472 + (w + 7) * 32 + quad * 8);
        acc3[0] = __builtin_amdgcn_mfma_f32_16x16x32_bf16(a0, bb, acc3[0], 0, 0, 0);
        acc3[1] = __builtin_amdgcn_mfma_f32_16x16x32_bf16(a1, bb, acc3[1], 0, 0, 0);
      }
    } else if (!cons && S < 7) {
      const int col = 32 * (S + 1);
      kan_feats28(An + tr * 472 + ej * 14, Hs[(col + ej) * 36 + tr]);
      kan_feats28(An + tr * 472 + (16 + ej) * 14, Hs[(col + 16 + ej) * 36 + tr]);
    }
    __syncthreads();
  }
  if (w < 7) {
#pragma unroll
    for (int m = 0; m < 2; ++m)
#pragma unroll
      for (int r = 0; r < 4; ++r)
        Red[w * 512 + (m * 16 + quad * 4 + r) * 16 + lr] = acc3[m][r];
  }
  __syncthreads();
  if (t < 512) {
    float s = (ej < 10) ? b3[ej] : 0.f;
#pragma unroll
    for (int ks = 0; ks < 7; ++ks) s += Red[ks * 512 + tr * 16 + ej];
    V[tr * 16 + ej] = s;
  }
  __syncthreads();
  if (t < 32) {
    float vv[10];
#pragma unroll
    for (int o = 0; o < 10; ++o) vv[o] = V[t * 16 + o];
    float mx = vv[0];
#pragma unroll
    for (int o = 1; o < 10; ++o) mx = fmaxf(mx, vv[o]);
    float se = 0.f;
#pragma unroll
    for (int o = 0; o < 10; ++o) se += expf(vv[o] - mx);
    const float l = mx + logf(se);
#pragma unroll
    for (int o = 0; o < 10; ++o) out[(size_t)(r0 + t) * 10 + o] = vv[o] - l;
  }
}

extern "C" void kernel_launch(void* const* d_in, const int* in_sizes, int n_in,
                              void* d_out, int out_size, void* d_ws, size_t ws_size,
                              hipStream_t stream) {
  const float* x = (const float*)d_in[0];
  const float* coef1 = (const float*)d_in[1];
  const float* sb1 = (const float*)d_in[2];
  const float* sp1 = (const float*)d_in[3];
  const float* b1 = (const float*)d_in[4];
  const float* coef2 = (const float*)d_in[5];
  const float* sb2 = (const float*)d_in[6];
  const float* sp2 = (const float*)d_in[7];
  const float* b2 = (const float*)d_in[8];
  const float* coef3 = (const float*)d_in[9];
  const float* sb3 = (const float*)d_in[10];
  const float* sp3 = (const float*)d_in[11];
  const float* b3 = (const float*)d_in[12];
  float* out = (float*)d_out;

  char* ws = (char*)d_ws;
  bf16* W1f = (bf16*)ws;              // 22 frags x 16 ntg x 1KB = 360448 B
  bf16* W2f = (bf16*)(ws + 360448);   // 112 x 16 x 1KB = 1835008 B
  bf16* W3f = (bf16*)(ws + 2195456);  // 112 x 1KB = 114688 B

  prep_all<<<322, 256, 0, stream>>>(coef1, sb1, sp1, coef2, sb2, sp2,
                                    coef3, sb3, sp3, W1f, W2f, W3f);
  meganet<<<256, 1024, 0, stream>>>(x, W1f, W2f, W3f, b1, b2, b3, out);
}

// Round 11
// 150.457 us; speedup vs baseline: 1.3672x; 1.0685x over previous
//
#include <hip/hip_runtime.h>
#include <hip/hip_bf16.h>

typedef __bf16 bf16x8_t __attribute__((ext_vector_type(8)));
typedef float f32x4_t __attribute__((ext_vector_type(4)));
using bf16 = __hip_bfloat16;

__device__ __forceinline__ unsigned short f2bf_bits(float v) {
  __hip_bfloat16 h = __float2bfloat16(v);
  return *reinterpret_cast<unsigned short*>(&h);
}

// mish(x) = x*tanh(softplus(x)) = x*n/(n+2) with n = e^x*(e^x+2).
__device__ __forceinline__ float mish_f(float x) {
  float z = __expf(x);
  float n = z * (z + 2.0f);
  float m = x * n / (n + 2.0f);
  return (x > 10.0f) ? x : m;
}

// 13 cubic B-spline basis values (grid 10, k=3, [-2,2]) + mish -> 28B LDS
// region. R0 sparse-store version.
__device__ __forceinline__ void kan_feats28(bf16* dst, float x) {
  unsigned int* d32 = (unsigned int*)dst;
#pragma unroll
  for (int d = 0; d < 7; ++d) d32[d] = 0u;
  float t = (x + 3.2f) * 2.5f;
  if (t >= 0.0f && t < 16.0f) {
    float tf = floorf(t);
    int c = (int)tf;
    float u = t - tf;
    float um = 1.0f - u;
    float u2 = u * u, u3 = u2 * u;
    const float s6 = 1.0f / 6.0f;
    float w0 = um * um * um * s6;
    float w1 = (3.0f * u3 - 6.0f * u2 + 4.0f) * s6;
    float w2 = (-3.0f * u3 + 3.0f * u2 + 3.0f * u + 1.0f) * s6;
    float w3 = u3 * s6;
    int j0 = c - 3;
    if (j0 >= 0)               dst[j0]     = __float2bfloat16(w0);
    if (j0 >= -1 && j0 <= 11)  dst[j0 + 1] = __float2bfloat16(w1);
    if (j0 >= -2 && j0 <= 10)  dst[j0 + 2] = __float2bfloat16(w2);
    if (j0 <= 9)               dst[j0 + 3] = __float2bfloat16(w3);
  }
  dst[13] = __float2bfloat16(mish_f(x));
}

// Coalesced weight pack. One block per k-frag-group s (W1f: 22, W2f: 112).
// Stage the <=4 source rows feeding s into LDS v[4][256][14] (coef*sp | sb)
// with CONTIGUOUS global reads (row*3328 + rm is sequential), then emit the
// fragment-major output as fully-coalesced consecutive dwords:
// dword index s*4096 + (t + j*256). Frag layout: [ntg:16][n:16][r2/2:16],
// element (n,r2) of frag (s,ntg) at (s*16+ntg)*512 + n*32 + r2 (r2=quad*8+el).
// k' = 32s + r2; source row i = k'/14, col r = k'%14; val = r<13 ?
// coef[i][o][r]*sp[i][o] : sb[i][o]; i >= NROWS -> 0 (k-pad).
// W3f (112 KB, 5%) keeps the proven scattered path (blocks 134..149).
__global__ __launch_bounds__(256) void prep_pack(
    const float* __restrict__ c1, const float* __restrict__ sp1, const float* __restrict__ sb1,
    const float* __restrict__ c2, const float* __restrict__ sp2, const float* __restrict__ sb2,
    const float* __restrict__ c3, const float* __restrict__ sp3, const float* __restrict__ sb3,
    bf16* __restrict__ W1f, bf16* __restrict__ W2f, bf16* __restrict__ W3f) {
  __shared__ float v[14336];  // [4][256][14]
  const int b = blockIdx.x, t = threadIdx.x;
  if (b < 134) {
    const bool isL1 = (b < 22);
    const int s = isL1 ? b : b - 22;
    const int NROWS = isL1 ? 49 : 256;
    const float* C = isL1 ? c1 : c2;
    const float* SP = isL1 ? sp1 : sp2;
    const float* SB = isL1 ? sb1 : sb2;
    unsigned int* W = (unsigned int*)(isL1 ? W1f : W2f);
    const int i0 = (32 * s) / 14;
    // Stage coef*sp: 4 rows x 3328 contiguous floats each.
#pragma unroll
    for (int k = 0; k < 52; ++k) {
      const int f = t + k * 256;        // [0, 13312)
      const int il = f / 3328;
      const int rm = f - il * 3328;     // row-local flat (o*13 + r)
      const int o = rm / 13;
      const int r = rm - o * 13;
      const int row = i0 + il;
      v[il * 3584 + o * 14 + r] =
          (row < NROWS) ? C[(size_t)row * 3328 + rm] * SP[(size_t)row * 256 + o] : 0.0f;
    }
    // Stage sb into r=13 slots.
#pragma unroll
    for (int j = 0; j < 4; ++j) {
      const int row = i0 + j;
      v[j * 3584 + t * 14 + 13] = (row < NROWS) ? SB[(size_t)row * 256 + t] : 0.0f;
    }
    __syncthreads();
    // Emit 16 coalesced dwords per thread.
#pragma unroll
    for (int j = 0; j < 16; ++j) {
      const int dw = t + j * 256;               // [0, 4096)
      const int ntg = dw >> 8, n = (dw >> 4) & 15, r2 = (dw & 15) * 2;
      const int o = ntg * 16 + n;
      const int ka = 32 * s + r2;
      const int ia = ka / 14, ra = ka - ia * 14;
      const int kb = ka + 1;
      const int ib = kb / 14, rb = kb - ib * 14;
      const unsigned int lo = f2bf_bits(v[(ia - i0) * 3584 + o * 14 + ra]);
      const unsigned int hi = f2bf_bits(v[(ib - i0) * 3584 + o * 14 + rb]);
      W[(size_t)s * 4096 + dw] = lo | (hi << 16);
    }
  } else {
    // W3f: proven scattered path (R3-fixed). 16 blocks x 256 = 4096 items.
    const int idx = (b - 134) * 256 + t;  // i in [0,256), o in [0,16)
    const int i = idx >> 4, o = idx & 15;
    float vals[14];
    if (o < 10) {
      const size_t io = (size_t)i * 10 + o;
      const float spv = sp3[io];
#pragma unroll
      for (int r = 0; r < 13; ++r) vals[r] = c3[io * 13 + r] * spv;
      vals[13] = sb3[io];
#pragma unroll
      for (int d = 0; d < 7; ++d) {
        const int k2 = i * 14 + 2 * d;
        const int s = k2 >> 5, r2 = k2 & 31;
        const size_t off = (size_t)s * 512 + o * 32 + (r2 >> 3) * 8 + (r2 & 7);
        *(unsigned int*)(W3f + off) = (unsigned int)f2bf_bits(vals[2 * d]) |
                                      ((unsigned int)f2bf_bits(vals[2 * d + 1]) << 16);
      }
    } else {
#pragma unroll
      for (int d = 0; d < 7; ++d) {
        const int k2 = i * 14 + 2 * d;
        const int s = k2 >> 5, r2 = k2 & 31;
        *(unsigned int*)(W3f + (size_t)s * 512 + o * 32 + (r2 >> 3) * 8 + (r2 & 7)) = 0u;
      }
    }
  }
}

// Megakernel v12 (R7 verbatim — best measured, 50.1us): R0 k-step machinery
// (plain loads, 4-deep compiler-placed FIFO, __syncthreads), phases C and E
// as 32-col super-chunks (14 k-steps per barrier / 2 per wave; producers
// batch 2 feats evals). A-buffers [32][472] bf16.
__global__ __launch_bounds__(1024, 4) void meganet(
    const float* __restrict__ x, const bf16* __restrict__ W1f,
    const bf16* __restrict__ W2f, const bf16* __restrict__ W3f,
    const float* __restrict__ b1, const float* __restrict__ b2,
    const float* __restrict__ b3, float* __restrict__ out) {
  __shared__ __align__(16) char lds[104448];
  float* const Hs = (float*)lds;             // [256][36] f32 transposed (36864)
  bf16* const A0 = (bf16*)(lds + 36864);     // [32][472] bf16 (30208)
  bf16* const A1 = (bf16*)(lds + 67072);     // [32][472] bf16 (30208)
  float* const P = (float*)(lds + 97280);    // [32][56] f32 (7168)
  float* const xs = (float*)lds;             // phase A only (50176)
  float* const Red = (float*)(lds + 36864);  // [7][32][16] f32 (E tail)
  float* const V = (float*)(lds + 67072);    // 32x16 f32

  const int t = threadIdx.x;
  const int w = t >> 6, lane = t & 63, quad = lane >> 4, lr = lane & 15;
  const int tr = (t >> 4) & 31, ej = t & 15;  // producer eval coords (t>=512)
  const int r0 = blockIdx.x * 32;
  const int foff = lr * 32 + quad * 8;
  const bool cons = (w < 8);
  const int ntg0 = 2 * w;  // consumer col-group base (valid w<8)

  // ---- Phase A: pool 32 images -> P[32][56] (staged via LDS) ----
  for (int h = 0; h < 2; ++h) {
    const float4* src = (const float4*)x + (size_t)(r0 + h * 16) * 196;
    float4* xd = (float4*)xs;
#pragma unroll
    for (int l = 0; l < 4; ++l) {
      const int idx = t + l * 1024;
      if (idx < 3136) xd[idx] = src[idx];
    }
    __syncthreads();
    if (t < 784) {
      const int img = t / 49, p = t - img * 49;
      const int oh = p / 7, ow = p - oh * 7;
      const float* xi = xs + img * 784 + oh * 112 + ow * 4;
      f32x4_t s4 = (f32x4_t){0.f, 0.f, 0.f, 0.f};
#pragma unroll
      for (int rr = 0; rr < 4; ++rr) {
        const f32x4_t v = *(const f32x4_t*)(xi + rr * 28);  // 16B-aligned
        s4 += v;
      }
      P[(h * 16 + img) * 56 + p] = (s4[0] + s4[1] + s4[2] + s4[3]) * (1.0f / 16.0f);
    }
    __syncthreads();
  }

  f32x4_t acc[2][2];
#pragma unroll
  for (int m = 0; m < 2; ++m)
#pragma unroll
    for (int n = 0; n < 2; ++n) acc[m][n] = (f32x4_t){0.f, 0.f, 0.f, 0.f};

  // ---- Phase B: layer-1, K=704 (22 k-frags: chunks 7,7,7,1; stride 232) ----
  bf16* const Bch0 = A0;
  bf16* const Bch1 = A1;
  bf16x8_t q0[4], q1[4];
  if (cons) {
#pragma unroll
    for (int s = 0; s < 4; ++s) {
      q0[s] = *(const bf16x8_t*)(W1f + (size_t)(s * 16 + ntg0) * 512 + foff);
      q1[s] = *(const bf16x8_t*)(W1f + (size_t)(s * 16 + ntg0 + 1) * 512 + foff);
    }
  } else {
    kan_feats28(Bch0 + tr * 232 + ej * 14, P[tr * 56 + ej]);  // chunk 0
  }
  __syncthreads();
#pragma unroll
  for (int c = 0; c < 4; ++c) {
    const bf16* const Ac = (c & 1) ? Bch1 : Bch0;
    bf16* const An = (c & 1) ? Bch0 : Bch1;
    if (cons) {
      const int nks = (c < 3) ? 7 : 1;
#pragma unroll
      for (int ks = 0; ks < 7; ++ks) {
        if (ks >= nks) continue;
        const int kk = c * 7 + ks;
        const int sl = kk & 3;
        bf16x8_t bb0 = q0[sl], bb1 = q1[sl];
        if (kk + 4 < 22) {
          q0[sl] = *(const bf16x8_t*)(W1f + (size_t)((kk + 4) * 16 + ntg0) * 512 + foff);
          q1[sl] = *(const bf16x8_t*)(W1f + (size_t)((kk + 4) * 16 + ntg0 + 1) * 512 + foff);
        }
#pragma unroll
        for (int m = 0; m < 2; ++m) {
          bf16x8_t a = *(const bf16x8_t*)(Ac + (m * 16 + lr) * 232 + ks * 32 + quad * 8);
          acc[m][0] = __builtin_amdgcn_mfma_f32_16x16x32_bf16(a, bb0, acc[m][0], 0, 0, 0);
          acc[m][1] = __builtin_amdgcn_mfma_f32_16x16x32_bf16(a, bb1, acc[m][1], 0, 0, 0);
        }
      }
    } else {
      if (c < 2) {
        kan_feats28(An + tr * 232 + ej * 14, P[tr * 56 + (c + 1) * 16 + ej]);
      } else if (c == 2) {
        if (ej == 0) kan_feats28(An + tr * 232, P[tr * 56 + 48]);
        else if (ej == 1) {
          unsigned int* z = (unsigned int*)(An + tr * 232 + 14);
#pragma unroll
          for (int d = 0; d < 9; ++d) z[d] = 0u;  // pad k 686..703
        }
      }
    }
    __syncthreads();
  }
  // H1 = acc + b1 -> Hs (transposed); consumers cover all 256 cols
  if (cons) {
#pragma unroll
    for (int m = 0; m < 2; ++m)
#pragma unroll
      for (int n = 0; n < 2; ++n) {
        const int col = w * 32 + n * 16 + lr;
        const float bn = b1[col];
        f32x4_t v;
#pragma unroll
        for (int r = 0; r < 4; ++r) v[r] = acc[m][n][r] + bn;
        *(f32x4_t*)(Hs + col * 36 + m * 16 + quad * 4) = v;
      }
  }
  __syncthreads();

  // ---- Phase C: layer-2, K=3584. 8 super-chunks x 14 k-steps (32 H-cols,
  //      stride 472). Producers: 2 feats evals/thread per SC. ----
#pragma unroll
  for (int m = 0; m < 2; ++m)
#pragma unroll
    for (int n = 0; n < 2; ++n) acc[m][n] = (f32x4_t){0.f, 0.f, 0.f, 0.f};
  if (cons) {
#pragma unroll
    for (int s = 0; s < 4; ++s) {
      q0[s] = *(const bf16x8_t*)(W2f + (size_t)(s * 16 + ntg0) * 512 + foff);
      q1[s] = *(const bf16x8_t*)(W2f + (size_t)(s * 16 + ntg0 + 1) * 512 + foff);
    }
  } else {  // SC0: cols 0..31
    kan_feats28(A0 + tr * 472 + ej * 14, Hs[ej * 36 + tr]);
    kan_feats28(A0 + tr * 472 + (16 + ej) * 14, Hs[(16 + ej) * 36 + tr]);
  }
  __syncthreads();
#pragma unroll
  for (int S = 0; S < 8; ++S) {
    const bf16* const Ac = (S & 1) ? A1 : A0;
    bf16* const An = (S & 1) ? A0 : A1;
    if (cons) {
#pragma unroll
      for (int ks = 0; ks < 14; ++ks) {
        const int kk = S * 14 + ks;
        const int sl = kk & 3;
        bf16x8_t bb0 = q0[sl], bb1 = q1[sl];
        if (kk + 4 < 112) {
          q0[sl] = *(const bf16x8_t*)(W2f + (size_t)((kk + 4) * 16 + ntg0) * 512 + foff);
          q1[sl] = *(const bf16x8_t*)(W2f + (size_t)((kk + 4) * 16 + ntg0 + 1) * 512 + foff);
        }
#pragma unroll
        for (int m = 0; m < 2; ++m) {
          bf16x8_t a = *(const bf16x8_t*)(Ac + (m * 16 + lr) * 472 + ks * 32 + quad * 8);
          acc[m][0] = __builtin_amdgcn_mfma_f32_16x16x32_bf16(a, bb0, acc[m][0], 0, 0, 0);
          acc[m][1] = __builtin_amdgcn_mfma_f32_16x16x32_bf16(a, bb1, acc[m][1], 0, 0, 0);
        }
      }
    } else if (S < 7) {
      const int col = 32 * (S + 1);
      kan_feats28(An + tr * 472 + ej * 14, Hs[(col + ej) * 36 + tr]);
      kan_feats28(An + tr * 472 + (16 + ej) * 14, Hs[(col + 16 + ej) * 36 + tr]);
    }
    __syncthreads();
  }
  // H2 = acc + b2 -> Hs (overwrite; H1 dead after SC7 feats)
  if (cons) {
#pragma unroll
    for (int m = 0; m < 2; ++m)
#pragma unroll
      for (int n = 0; n < 2; ++n) {
        const int col = w * 32 + n * 16 + lr;
        const float bn = b2[col];
        f32x4_t v;
#pragma unroll
        for (int r = 0; r < 4; ++r) v[r] = acc[m][n][r] + bn;
        *(f32x4_t*)(Hs + col * 36 + m * 16 + quad * 4) = v;
      }
  }
  __syncthreads();

  // ---- Phase E: layer-3 (N=16, 10 real). 8 super-chunks; consumer waves
  //      0..6 do 2 k-steps each per SC (k-slots w and w+7); producers =
  //      waves 8..15 (2 feats evals/thread per SC). ----
  f32x4_t acc3[2];
  acc3[0] = (f32x4_t){0.f, 0.f, 0.f, 0.f};
  acc3[1] = acc3[0];
  bf16x8_t q3[4];
  if (w < 7) {
#pragma unroll
    for (int s = 0; s < 4; ++s)
      q3[s] = *(const bf16x8_t*)(W3f + (size_t)(s * 7 + w) * 512 + foff);
  } else if (!cons) {  // SC0: cols 0..31
    kan_feats28(A0 + tr * 472 + ej * 14, Hs[ej * 36 + tr]);
    kan_feats28(A0 + tr * 472 + (16 + ej) * 14, Hs[(16 + ej) * 36 + tr]);
  }
  __syncthreads();
#pragma unroll
  for (int S = 0; S < 8; ++S) {
    const bf16* const Ac = (S & 1) ? A1 : A0;
    bf16* const An = (S & 1) ? A0 : A1;
    if (w < 7) {
      {  // k-step 1: frag-chunk c0 = 2S, local ks = w
        const int c0 = 2 * S;
        bf16x8_t bb = q3[c0 & 3];
        if (c0 + 4 < 16)
          q3[c0 & 3] = *(const bf16x8_t*)(W3f + (size_t)((c0 + 4) * 7 + w) * 512 + foff);
        bf16x8_t a0 = *(const bf16x8_t*)(Ac + lr * 472 + w * 32 + quad * 8);
        bf16x8_t a1 = *(const bf16x8_t*)(Ac + (16 + lr) * 472 + w * 32 + quad * 8);
        acc3[0] = __builtin_amdgcn_mfma_f32_16x16x32_bf16(a0, bb, acc3[0], 0, 0, 0);
        acc3[1] = __builtin_amdgcn_mfma_f32_16x16x32_bf16(a1, bb, acc3[1], 0, 0, 0);
      }
      {  // k-step 2: frag-chunk c1 = 2S+1, local ks = w+7
        const int c1 = 2 * S + 1;
        bf16x8_t bb = q3[c1 & 3];
        if (c1 + 4 < 16)
          q3[c1 & 3] = *(const bf16x8_t*)(W3f + (size_t)((c1 + 4) * 7 + w) * 512 + foff);
        bf16x8_t a0 = *(const bf16x8_t*)(Ac + lr * 472 + (w + 7) * 32 + quad * 8);
        bf16x8_t a1 = *(const bf16x8_t*)(Ac + (16 + lr) * 472 + (w + 7) * 32 + quad * 8);
        acc3[0] = __builtin_amdgcn_mfma_f32_16x16x32_bf16(a0, bb, acc3[0], 0, 0, 0);
        acc3[1] = __builtin_amdgcn_mfma_f32_16x16x32_bf16(a1, bb, acc3[1], 0, 0, 0);
      }
    } else if (!cons && S < 7) {
      const int col = 32 * (S + 1);
      kan_feats28(An + tr * 472 + ej * 14, Hs[(col + ej) * 36 + tr]);
      kan_feats28(An + tr * 472 + (16 + ej) * 14, Hs[(col + 16 + ej) * 36 + tr]);
    }
    __syncthreads();
  }
  if (w < 7) {
#pragma unroll
    for (int m = 0; m < 2; ++m)
#pragma unroll
      for (int r = 0; r < 4; ++r)
        Red[w * 512 + (m * 16 + quad * 4 + r) * 16 + lr] = acc3[m][r];
  }
  __syncthreads();
  if (t < 512) {
    float s = (ej < 10) ? b3[ej] : 0.f;
#pragma unroll
    for (int ks = 0; ks < 7; ++ks) s += Red[ks * 512 + tr * 16 + ej];
    V[tr * 16 + ej] = s;
  }
  __syncthreads();
  if (t < 32) {
    float vv[10];
#pragma unroll
    for (int o = 0; o < 10; ++o) vv[o] = V[t * 16 + o];
    float mx = vv[0];
#pragma unroll
    for (int o = 1; o < 10; ++o) mx = fmaxf(mx, vv[o]);
    float se = 0.f;
#pragma unroll
    for (int o = 0; o < 10; ++o) se += expf(vv[o] - mx);
    const float l = mx + logf(se);
#pragma unroll
    for (int o = 0; o < 10; ++o) out[(size_t)(r0 + t) * 10 + o] = vv[o] - l;
  }
}

extern "C" void kernel_launch(void* const* d_in, const int* in_sizes, int n_in,
                              void* d_out, int out_size, void* d_ws, size_t ws_size,
                              hipStream_t stream) {
  const float* x = (const float*)d_in[0];
  const float* coef1 = (const float*)d_in[1];
  const float* sb1 = (const float*)d_in[2];
  const float* sp1 = (const float*)d_in[3];
  const float* b1 = (const float*)d_in[4];
  const float* coef2 = (const float*)d_in[5];
  const float* sb2 = (const float*)d_in[6];
  const float* sp2 = (const float*)d_in[7];
  const float* b2 = (const float*)d_in[8];
  const float* coef3 = (const float*)d_in[9];
  const float* sb3 = (const float*)d_in[10];
  const float* sp3 = (const float*)d_in[11];
  const float* b3 = (const float*)d_in[12];
  float* out = (float*)d_out;

  char* ws = (char*)d_ws;
  bf16* W1f = (bf16*)ws;              // 22 frags x 16 ntg x 1KB = 360448 B
  bf16* W2f = (bf16*)(ws + 360448);   // 112 x 16 x 1KB = 1835008 B
  bf16* W3f = (bf16*)(ws + 2195456);  // 112 x 1KB = 114688 B

  prep_pack<<<150, 256, 0, stream>>>(coef1, sp1, sb1, coef2, sp2, sb2,
                                     coef3, sp3, sb3, W1f, W2f, W3f);
  meganet<<<256, 1024, 0, stream>>>(x, W1f, W2f, W3f, b1, b2, b3, out);
}

// Round 12
// 137.724 us; speedup vs baseline: 1.4936x; 1.0925x over previous
//
#include <hip/hip_runtime.h>
#include <hip/hip_bf16.h>

typedef __bf16 bf16x8_t __attribute__((ext_vector_type(8)));
typedef float f32x4_t __attribute__((ext_vector_type(4)));
using bf16 = __hip_bfloat16;

__device__ __forceinline__ unsigned short f2bf_bits(float v) {
  __hip_bfloat16 h = __float2bfloat16(v);
  return *reinterpret_cast<unsigned short*>(&h);
}

// mish(x) = x*tanh(softplus(x)) = x*n/(n+2) with n = e^x*(e^x+2).
__device__ __forceinline__ float mish_f(float x) {
  float z = __expf(x);
  float n = z * (z + 2.0f);
  float m = x * n / (n + 2.0f);
  return (x > 10.0f) ? x : m;
}

// 13 cubic B-spline basis values (grid 10, k=3, [-2,2]) + mish -> 28B LDS
// region. R0 sparse-store version (branch-free selects doubled VALUBusy in
// R4 — keep sparse).
__device__ __forceinline__ void kan_feats28(bf16* dst, float x) {
  unsigned int* d32 = (unsigned int*)dst;
#pragma unroll
  for (int d = 0; d < 7; ++d) d32[d] = 0u;
  float t = (x + 3.2f) * 2.5f;
  if (t >= 0.0f && t < 16.0f) {
    float tf = floorf(t);
    int c = (int)tf;
    float u = t - tf;
    float um = 1.0f - u;
    float u2 = u * u, u3 = u2 * u;
    const float s6 = 1.0f / 6.0f;
    float w0 = um * um * um * s6;
    float w1 = (3.0f * u3 - 6.0f * u2 + 4.0f) * s6;
    float w2 = (-3.0f * u3 + 3.0f * u2 + 3.0f * u + 1.0f) * s6;
    float w3 = u3 * s6;
    int j0 = c - 3;
    if (j0 >= 0)               dst[j0]     = __float2bfloat16(w0);
    if (j0 >= -1 && j0 <= 11)  dst[j0 + 1] = __float2bfloat16(w1);
    if (j0 >= -2 && j0 <= 10)  dst[j0 + 2] = __float2bfloat16(w2);
    if (j0 <= 9)               dst[j0 + 3] = __float2bfloat16(w3);
  }
  dst[13] = __float2bfloat16(mish_f(x));
}

// Builds W1f, W2f, W3f — ALL MFMA-fragment-major. Frag s (global k-frag of 32)
// x ntg (group of 16 N-rows): 512 elements (1KB); element (n,quad,el) at
// (s*16+ntg)*512 + n*32 + quad*8 + el. Packed grid (322 blocks):
//   b<49: L1 (i=b, o=t) | b==49: L1 k-pad | 50<=b<306: L2 (i=b-50, o=t)
//   306<=b<322: L3 items idx=(b-306)*256+t (4096 = 256 rows x 16 cols).
__global__ __launch_bounds__(256) void prep_all(
    const float* __restrict__ c1, const float* __restrict__ sb1, const float* __restrict__ sp1,
    const float* __restrict__ c2, const float* __restrict__ sb2, const float* __restrict__ sp2,
    const float* __restrict__ c3, const float* __restrict__ sb3, const float* __restrict__ sp3,
    bf16* __restrict__ W1f, bf16* __restrict__ W2f, bf16* __restrict__ W3f) {
  const int b = blockIdx.x, t = threadIdx.x;
  float vals[14];
  if (b < 49) {
    const int i = b, o = t;
    const int ntg = o >> 4, lrr = o & 15;
    const size_t io = (size_t)i * 256 + o;
    const float spv = sp1[io];
#pragma unroll
    for (int r = 0; r < 13; ++r) vals[r] = c1[io * 13 + r] * spv;
    vals[13] = sb1[io];
#pragma unroll
    for (int d = 0; d < 7; ++d) {
      const int k2 = i * 14 + 2 * d;
      const int s = k2 >> 5, r2 = k2 & 31;
      const size_t off = ((size_t)(s * 16 + ntg)) * 512 + lrr * 32 + (r2 >> 3) * 8 + (r2 & 7);
      *(unsigned int*)(W1f + off) = (unsigned int)f2bf_bits(vals[2 * d]) |
                                    ((unsigned int)f2bf_bits(vals[2 * d + 1]) << 16);
    }
  } else if (b == 49) {
    const int ntg = t >> 4, lrr = t & 15;
#pragma unroll
    for (int d = 0; d < 9; ++d) {
      const int k2 = 686 + 2 * d;
      const int r2 = k2 & 31;
      *(unsigned int*)(W1f + ((size_t)(21 * 16 + ntg)) * 512 + lrr * 32 + (r2 >> 3) * 8 + (r2 & 7)) = 0u;
    }
  } else if (b < 306) {
    const int i = b - 50;
    const int o = t;
    const int ntg = o >> 4, lrr = o & 15;
    const size_t io = (size_t)i * 256 + o;
    const float spv = sp2[io];
#pragma unroll
    for (int r = 0; r < 13; ++r) vals[r] = c2[io * 13 + r] * spv;
    vals[13] = sb2[io];
#pragma unroll
    for (int d = 0; d < 7; ++d) {
      const int k2 = i * 14 + 2 * d;
      const int s = k2 >> 5, r2 = k2 & 31;
      const size_t off = ((size_t)(s * 16 + ntg)) * 512 + lrr * 32 + (r2 >> 3) * 8 + (r2 & 7);
      *(unsigned int*)(W2f + off) = (unsigned int)f2bf_bits(vals[2 * d]) |
                                    ((unsigned int)f2bf_bits(vals[2 * d + 1]) << 16);
    }
  } else {
    const int idx = (b - 306) * 256 + t;  // 4096 items: i in [0,256), o in [0,16)
    const int i = idx >> 4, o = idx & 15;
    if (o < 10) {
      const size_t io = (size_t)i * 10 + o;
      const float spv = sp3[io];
#pragma unroll
      for (int r = 0; r < 13; ++r) vals[r] = c3[io * 13 + r] * spv;
      vals[13] = sb3[io];
#pragma unroll
      for (int d = 0; d < 7; ++d) {
        const int k2 = i * 14 + 2 * d;
        const int s = k2 >> 5, r2 = k2 & 31;
        const size_t off = (size_t)s * 512 + o * 32 + (r2 >> 3) * 8 + (r2 & 7);
        *(unsigned int*)(W3f + off) = (unsigned int)f2bf_bits(vals[2 * d]) |
                                      ((unsigned int)f2bf_bits(vals[2 * d + 1]) << 16);
      }
    } else {
#pragma unroll
      for (int d = 0; d < 7; ++d) {
        const int k2 = i * 14 + 2 * d;
        const int s = k2 >> 5, r2 = k2 & 31;
        *(unsigned int*)(W3f + (size_t)s * 512 + o * 32 + (r2 >> 3) * 8 + (r2 & 7)) = 0u;
      }
    }
  }
}

// Megakernel v12 (session best, 50.1us meganet / 139.1us total): R0 k-step
// machinery (plain loads, 4-deep compiler-placed FIFO, __syncthreads),
// phases C and E as 32-col super-chunks (14 k-steps per barrier / 2 per
// wave; producers batch 2 feats evals). A-buffers [32][472] bf16.
__global__ __launch_bounds__(1024, 4) void meganet(
    const float* __restrict__ x, const bf16* __restrict__ W1f,
    const bf16* __restrict__ W2f, const bf16* __restrict__ W3f,
    const float* __restrict__ b1, const float* __restrict__ b2,
    const float* __restrict__ b3, float* __restrict__ out) {
  __shared__ __align__(16) char lds[104448];
  float* const Hs = (float*)lds;             // [256][36] f32 transposed (36864)
  bf16* const A0 = (bf16*)(lds + 36864);     // [32][472] bf16 (30208)
  bf16* const A1 = (bf16*)(lds + 67072);     // [32][472] bf16 (30208)
  float* const P = (float*)(lds + 97280);    // [32][56] f32 (7168)
  float* const xs = (float*)lds;             // phase A only (50176)
  float* const Red = (float*)(lds + 36864);  // [7][32][16] f32 (E tail)
  float* const V = (float*)(lds + 67072);    // 32x16 f32

  const int t = threadIdx.x;
  const int w = t >> 6, lane = t & 63, quad = lane >> 4, lr = lane & 15;
  const int tr = (t >> 4) & 31, ej = t & 15;  // producer eval coords (t>=512)
  const int r0 = blockIdx.x * 32;
  const int foff = lr * 32 + quad * 8;
  const bool cons = (w < 8);
  const int ntg0 = 2 * w;  // consumer col-group base (valid w<8)

  // ---- Phase A: pool 32 images -> P[32][56] (staged via LDS) ----
  for (int h = 0; h < 2; ++h) {
    const float4* src = (const float4*)x + (size_t)(r0 + h * 16) * 196;
    float4* xd = (float4*)xs;
#pragma unroll
    for (int l = 0; l < 4; ++l) {
      const int idx = t + l * 1024;
      if (idx < 3136) xd[idx] = src[idx];
    }
    __syncthreads();
    if (t < 784) {
      const int img = t / 49, p = t - img * 49;
      const int oh = p / 7, ow = p - oh * 7;
      const float* xi = xs + img * 784 + oh * 112 + ow * 4;
      f32x4_t s4 = (f32x4_t){0.f, 0.f, 0.f, 0.f};
#pragma unroll
      for (int rr = 0; rr < 4; ++rr) {
        const f32x4_t v = *(const f32x4_t*)(xi + rr * 28);  // 16B-aligned
        s4 += v;
      }
      P[(h * 16 + img) * 56 + p] = (s4[0] + s4[1] + s4[2] + s4[3]) * (1.0f / 16.0f);
    }
    __syncthreads();
  }

  f32x4_t acc[2][2];
#pragma unroll
  for (int m = 0; m < 2; ++m)
#pragma unroll
    for (int n = 0; n < 2; ++n) acc[m][n] = (f32x4_t){0.f, 0.f, 0.f, 0.f};

  // ---- Phase B: layer-1, K=704 (22 k-frags: chunks 7,7,7,1; stride 232) ----
  bf16* const Bch0 = A0;
  bf16* const Bch1 = A1;
  bf16x8_t q0[4], q1[4];
  if (cons) {
#pragma unroll
    for (int s = 0; s < 4; ++s) {
      q0[s] = *(const bf16x8_t*)(W1f + (size_t)(s * 16 + ntg0) * 512 + foff);
      q1[s] = *(const bf16x8_t*)(W1f + (size_t)(s * 16 + ntg0 + 1) * 512 + foff);
    }
  } else {
    kan_feats28(Bch0 + tr * 232 + ej * 14, P[tr * 56 + ej]);  // chunk 0
  }
  __syncthreads();
#pragma unroll
  for (int c = 0; c < 4; ++c) {
    const bf16* const Ac = (c & 1) ? Bch1 : Bch0;
    bf16* const An = (c & 1) ? Bch0 : Bch1;
    if (cons) {
      const int nks = (c < 3) ? 7 : 1;
#pragma unroll
      for (int ks = 0; ks < 7; ++ks) {
        if (ks >= nks) continue;
        const int kk = c * 7 + ks;
        const int sl = kk & 3;
        bf16x8_t bb0 = q0[sl], bb1 = q1[sl];
        if (kk + 4 < 22) {
          q0[sl] = *(const bf16x8_t*)(W1f + (size_t)((kk + 4) * 16 + ntg0) * 512 + foff);
          q1[sl] = *(const bf16x8_t*)(W1f + (size_t)((kk + 4) * 16 + ntg0 + 1) * 512 + foff);
        }
#pragma unroll
        for (int m = 0; m < 2; ++m) {
          bf16x8_t a = *(const bf16x8_t*)(Ac + (m * 16 + lr) * 232 + ks * 32 + quad * 8);
          acc[m][0] = __builtin_amdgcn_mfma_f32_16x16x32_bf16(a, bb0, acc[m][0], 0, 0, 0);
          acc[m][1] = __builtin_amdgcn_mfma_f32_16x16x32_bf16(a, bb1, acc[m][1], 0, 0, 0);
        }
      }
    } else {
      if (c < 2) {
        kan_feats28(An + tr * 232 + ej * 14, P[tr * 56 + (c + 1) * 16 + ej]);
      } else if (c == 2) {
        if (ej == 0) kan_feats28(An + tr * 232, P[tr * 56 + 48]);
        else if (ej == 1) {
          unsigned int* z = (unsigned int*)(An + tr * 232 + 14);
#pragma unroll
          for (int d = 0; d < 9; ++d) z[d] = 0u;  // pad k 686..703
        }
      }
    }
    __syncthreads();
  }
  // H1 = acc + b1 -> Hs (transposed); consumers cover all 256 cols
  if (cons) {
#pragma unroll
    for (int m = 0; m < 2; ++m)
#pragma unroll
      for (int n = 0; n < 2; ++n) {
        const int col = w * 32 + n * 16 + lr;
        const float bn = b1[col];
        f32x4_t v;
#pragma unroll
        for (int r = 0; r < 4; ++r) v[r] = acc[m][n][r] + bn;
        *(f32x4_t*)(Hs + col * 36 + m * 16 + quad * 4) = v;
      }
  }
  __syncthreads();

  // ---- Phase C: layer-2, K=3584. 8 super-chunks x 14 k-steps (32 H-cols,
  //      stride 472). Producers: 2 feats evals/thread per SC. ----
#pragma unroll
  for (int m = 0; m < 2; ++m)
#pragma unroll
    for (int n = 0; n < 2; ++n) acc[m][n] = (f32x4_t){0.f, 0.f, 0.f, 0.f};
  if (cons) {
#pragma unroll
    for (int s = 0; s < 4; ++s) {
      q0[s] = *(const bf16x8_t*)(W2f + (size_t)(s * 16 + ntg0) * 512 + foff);
      q1[s] = *(const bf16x8_t*)(W2f + (size_t)(s * 16 + ntg0 + 1) * 512 + foff);
    }
  } else {  // SC0: cols 0..31
    kan_feats28(A0 + tr * 472 + ej * 14, Hs[ej * 36 + tr]);
    kan_feats28(A0 + tr * 472 + (16 + ej) * 14, Hs[(16 + ej) * 36 + tr]);
  }
  __syncthreads();
#pragma unroll
  for (int S = 0; S < 8; ++S) {
    const bf16* const Ac = (S & 1) ? A1 : A0;
    bf16* const An = (S & 1) ? A0 : A1;
    if (cons) {
#pragma unroll
      for (int ks = 0; ks < 14; ++ks) {
        const int kk = S * 14 + ks;
        const int sl = kk & 3;
        bf16x8_t bb0 = q0[sl], bb1 = q1[sl];
        if (kk + 4 < 112) {
          q0[sl] = *(const bf16x8_t*)(W2f + (size_t)((kk + 4) * 16 + ntg0) * 512 + foff);
          q1[sl] = *(const bf16x8_t*)(W2f + (size_t)((kk + 4) * 16 + ntg0 + 1) * 512 + foff);
        }
#pragma unroll
        for (int m = 0; m < 2; ++m) {
          bf16x8_t a = *(const bf16x8_t*)(Ac + (m * 16 + lr) * 472 + ks * 32 + quad * 8);
          acc[m][0] = __builtin_amdgcn_mfma_f32_16x16x32_bf16(a, bb0, acc[m][0], 0, 0, 0);
          acc[m][1] = __builtin_amdgcn_mfma_f32_16x16x32_bf16(a, bb1, acc[m][1], 0, 0, 0);
        }
      }
    } else if (S < 7) {
      const int col = 32 * (S + 1);
      kan_feats28(An + tr * 472 + ej * 14, Hs[(col + ej) * 36 + tr]);
      kan_feats28(An + tr * 472 + (16 + ej) * 14, Hs[(col + 16 + ej) * 36 + tr]);
    }
    __syncthreads();
  }
  // H2 = acc + b2 -> Hs (overwrite; H1 dead after SC7 feats)
  if (cons) {
#pragma unroll
    for (int m = 0; m < 2; ++m)
#pragma unroll
      for (int n = 0; n < 2; ++n) {
        const int col = w * 32 + n * 16 + lr;
        const float bn = b2[col];
        f32x4_t v;
#pragma unroll
        for (int r = 0; r < 4; ++r) v[r] = acc[m][n][r] + bn;
        *(f32x4_t*)(Hs + col * 36 + m * 16 + quad * 4) = v;
      }
  }
  __syncthreads();

  // ---- Phase E: layer-3 (N=16, 10 real). 8 super-chunks; consumer waves
  //      0..6 do 2 k-steps each per SC (k-slots w and w+7); producers =
  //      waves 8..15 (2 feats evals/thread per SC). ----
  f32x4_t acc3[2];
  acc3[0] = (f32x4_t){0.f, 0.f, 0.f, 0.f};
  acc3[1] = acc3[0];
  bf16x8_t q3[4];
  if (w < 7) {
#pragma unroll
    for (int s = 0; s < 4; ++s)
      q3[s] = *(const bf16x8_t*)(W3f + (size_t)(s * 7 + w) * 512 + foff);
  } else if (!cons) {  // SC0: cols 0..31
    kan_feats28(A0 + tr * 472 + ej * 14, Hs[ej * 36 + tr]);
    kan_feats28(A0 + tr * 472 + (16 + ej) * 14, Hs[(16 + ej) * 36 + tr]);
  }
  __syncthreads();
#pragma unroll
  for (int S = 0; S < 8; ++S) {
    const bf16* const Ac = (S & 1) ? A1 : A0;
    bf16* const An = (S & 1) ? A0 : A1;
    if (w < 7) {
      {  // k-step 1: frag-chunk c0 = 2S, local ks = w
        const int c0 = 2 * S;
        bf16x8_t bb = q3[c0 & 3];
        if (c0 + 4 < 16)
          q3[c0 & 3] = *(const bf16x8_t*)(W3f + (size_t)((c0 + 4) * 7 + w) * 512 + foff);
        bf16x8_t a0 = *(const bf16x8_t*)(Ac + lr * 472 + w * 32 + quad * 8);
        bf16x8_t a1 = *(const bf16x8_t*)(Ac + (16 + lr) * 472 + w * 32 + quad * 8);
        acc3[0] = __builtin_amdgcn_mfma_f32_16x16x32_bf16(a0, bb, acc3[0], 0, 0, 0);
        acc3[1] = __builtin_amdgcn_mfma_f32_16x16x32_bf16(a1, bb, acc3[1], 0, 0, 0);
      }
      {  // k-step 2: frag-chunk c1 = 2S+1, local ks = w+7
        const int c1 = 2 * S + 1;
        bf16x8_t bb = q3[c1 & 3];
        if (c1 + 4 < 16)
          q3[c1 & 3] = *(const bf16x8_t*)(W3f + (size_t)((c1 + 4) * 7 + w) * 512 + foff);
        bf16x8_t a0 = *(const bf16x8_t*)(Ac + lr * 472 + (w + 7) * 32 + quad * 8);
        bf16x8_t a1 = *(const bf16x8_t*)(Ac + (16 + lr) * 472 + (w + 7) * 32 + quad * 8);
        acc3[0] = __builtin_amdgcn_mfma_f32_16x16x32_bf16(a0, bb, acc3[0], 0, 0, 0);
        acc3[1] = __builtin_amdgcn_mfma_f32_16x16x32_bf16(a1, bb, acc3[1], 0, 0, 0);
      }
    } else if (!cons && S < 7) {
      const int col = 32 * (S + 1);
      kan_feats28(An + tr * 472 + ej * 14, Hs[(col + ej) * 36 + tr]);
      kan_feats28(An + tr * 472 + (16 + ej) * 14, Hs[(col + 16 + ej) * 36 + tr]);
    }
    __syncthreads();
  }
  if (w < 7) {
#pragma unroll
    for (int m = 0; m < 2; ++m)
#pragma unroll
      for (int r = 0; r < 4; ++r)
        Red[w * 512 + (m * 16 + quad * 4 + r) * 16 + lr] = acc3[m][r];
  }
  __syncthreads();
  if (t < 512) {
    float s = (ej < 10) ? b3[ej] : 0.f;
#pragma unroll
    for (int ks = 0; ks < 7; ++ks) s += Red[ks * 512 + tr * 16 + ej];
    V[tr * 16 + ej] = s;
  }
  __syncthreads();
  if (t < 32) {
    float vv[10];
#pragma unroll
    for (int o = 0; o < 10; ++o) vv[o] = V[t * 16 + o];
    float mx = vv[0];
#pragma unroll
    for (int o = 1; o < 10; ++o) mx = fmaxf(mx, vv[o]);
    float se = 0.f;
#pragma unroll
    for (int o = 0; o < 10; ++o) se += expf(vv[o] - mx);
    const float l = mx + logf(se);
#pragma unroll
    for (int o = 0; o < 10; ++o) out[(size_t)(r0 + t) * 10 + o] = vv[o] - l;
  }
}

extern "C" void kernel_launch(void* const* d_in, const int* in_sizes, int n_in,
                              void* d_out, int out_size, void* d_ws, size_t ws_size,
                              hipStream_t stream) {
  const float* x = (const float*)d_in[0];
  const float* coef1 = (const float*)d_in[1];
  const float* sb1 = (const float*)d_in[2];
  const float* sp1 = (const float*)d_in[3];
  const float* b1 = (const float*)d_in[4];
  const float* coef2 = (const float*)d_in[5];
  const float* sb2 = (const float*)d_in[6];
  const float* sp2 = (const float*)d_in[7];
  const float* b2 = (const float*)d_in[8];
  const float* coef3 = (const float*)d_in[9];
  const float* sb3 = (const float*)d_in[10];
  const float* sp3 = (const float*)d_in[11];
  const float* b3 = (const float*)d_in[12];
  float* out = (float*)d_out;

  char* ws = (char*)d_ws;
  bf16* W1f = (bf16*)ws;              // 22 frags x 16 ntg x 1KB = 360448 B
  bf16* W2f = (bf16*)(ws + 360448);   // 112 x 16 x 1KB = 1835008 B
  bf16* W3f = (bf16*)(ws + 2195456);  // 112 x 1KB = 114688 B

  prep_all<<<322, 256, 0, stream>>>(coef1, sb1, sp1, coef2, sb2, sp2,
                                    coef3, sb3, sp3, W1f, W2f, W3f);
  meganet<<<256, 1024, 0, stream>>>(x, W1f, W2f, W3f, b1, b2, b3, out);
}